// Round 1
// baseline (1178.267 us; speedup 1.0000x reference)
//
#include <hip/hip_runtime.h>
#include <math.h>

// ---------------- problem constants ----------------
static constexpr int NB = 2;          // batch
static constexpr int NC = 64;         // channels
static constexpr int NHp = 128, NWp = 128;
static constexpr int NL = NHp * NWp;  // 16384
static constexpr int NCR = 16;        // reduced channels
static constexpr int HHH = 64;        // half resolution
static constexpr int NL2 = HHH * HHH; // 4096
static constexpr int NHASH = 4;
static constexpr int CHUNKSZ = 512;
static constexpr int NCHUNKS = 32;    // NL / CHUNKSZ
static constexpr int TOT = NHASH * NL;   // 65536 per batch
static constexpr int NKEY = 128;         // 32 buckets * 4 hashes
static constexpr int NTILE = 256;        // sort tiles per batch
static constexpr int TILESZ = TOT / NTILE; // 256

// ---------------- workspace layout (float offsets) ----------------
static constexpr size_t OFF_MASK = 0;
static constexpr size_t OFF_FEA  = OFF_MASK + (size_t)NB*NC*NL;            // 2,097,152
static constexpr size_t OFF_XE   = OFF_FEA  + (size_t)NB*NC*NL;            // 4,194,304
static constexpr size_t OFF_XEN  = OFF_XE   + (size_t)NB*NL*NCR;           // 4,718,592
static constexpr size_t OFF_YE   = OFF_XEN  + (size_t)NB*NL*NCR;           // 5,242,880
static constexpr size_t OFF_RET  = OFF_YE   + (size_t)NB*NL*NC;            // 7,340,032
static constexpr size_t OFF_BSC  = OFF_RET  + (size_t)NB*TOT*NC;           // 15,728,640
static constexpr size_t OFF_INT  = OFF_BSC  + (size_t)NB*TOT;              // 15,859,712 (ints)
// int offsets (in ints) relative to int base:
static constexpr size_t IOFF_CODES = 0;
static constexpr size_t IOFF_IDX   = IOFF_CODES + (size_t)NB*TOT;
static constexpr size_t IOFF_UNDO  = IOFF_IDX   + (size_t)NB*TOT;
static constexpr size_t IOFF_HIST  = IOFF_UNDO  + (size_t)NB*TOT;
static constexpr size_t IOFF_OFFS  = IOFF_HIST  + (size_t)NB*NKEY*NTILE;
static constexpr size_t IOFF_END   = IOFF_OFFS  + (size_t)NB*NKEY*NTILE;
// small float buffers after the int region (ints are 4B like floats):
static constexpr size_t OFF_CAY = OFF_INT + IOFF_END;
static constexpr size_t OFF_CAS = OFF_CAY + (size_t)NB*NC;
// phase-1 overlay: lives inside [OFF_RET, OFF_BSC) which is written later
static constexpr size_t OFF_XR    = OFF_RET;
static constexpr size_t OFF_FEATS = OFF_XR    + (size_t)NB*NCR*NL;
static constexpr size_t OFF_PMX   = OFF_FEATS + (size_t)NB*8*NCR*NL;
static constexpr size_t OFF_PAV   = OFF_PMX   + (size_t)NB*NCR*NL2;
static constexpr size_t OFF_PTMP  = OFF_PAV   + (size_t)NB*NCR*NL2;
static constexpr size_t OFF_DWT   = OFF_PTMP  + (size_t)NB*NCR*NL2;
static constexpr size_t OFF_PRE   = OFF_DWT   + (size_t)NB*NCR*NL2;
static_assert(OFF_PRE + (size_t)NB*NC*NL <= OFF_BSC, "phase-1 overlay must fit in ret region");

__device__ __forceinline__ float sigmoidf_(float v){ return 1.0f/(1.0f + expf(-v)); }

// ---------------- phase 1: spatial attention ----------------

// xr = conv1x1(x, 64->16) + b
__global__ void k_xr(const float* __restrict__ x, const float* __restrict__ w,
                     const float* __restrict__ b, float* __restrict__ xr){
  int gid = blockIdx.x*256 + threadIdx.x;
  if (gid >= NB*NCR*NL) return;
  int p = gid & (NL-1); int t = gid >> 14; int oc = t & 15; int bb = t >> 4;
  const float* xi = x + (size_t)bb*NC*NL + p;
  float s = b[oc];
  #pragma unroll
  for (int ic=0; ic<NC; ++ic) s += xi[(size_t)ic*NL] * w[oc*NC+ic];
  xr[gid] = s;
}

// s0 = dw1x1(pw(xr,16->32)) -> feats channels [0,32)
__global__ void k_s0(const float* __restrict__ xr, const float* __restrict__ pw,
                     const float* __restrict__ dww, const float* __restrict__ dwb,
                     float* __restrict__ feats){
  int gid = blockIdx.x*256 + threadIdx.x;
  if (gid >= NB*32*NL) return;
  int p = gid & (NL-1); int t = gid >> 14; int oc = t & 31; int bb = t >> 5;
  const float* xi = xr + (size_t)bb*NCR*NL + p;
  float s = 0.f;
  #pragma unroll
  for (int ic=0; ic<NCR; ++ic) s += xi[(size_t)ic*NL] * pw[oc*NCR+ic];
  feats[(size_t)bb*128*NL + (size_t)oc*NL + p] = s*dww[oc] + dwb[oc];
}

// 2x2 max + avg pool of xr -> [B,16,64,64]
__global__ void k_pool(const float* __restrict__ xr, float* __restrict__ pmax,
                       float* __restrict__ pavg){
  int gid = blockIdx.x*256 + threadIdx.x;
  if (gid >= NB*NCR*NL2) return;
  int p = gid & (NL2-1); int t = gid >> 12; int c = t & 15; int bb = t >> 4;
  int y = p >> 6, x2 = p & 63;
  const float* base = xr + (size_t)(bb*NCR + c)*NL + (size_t)(2*y)*NWp + 2*x2;
  float a = base[0], b_ = base[1], c_ = base[NWp], d = base[NWp+1];
  pmax[gid] = fmaxf(fmaxf(a,b_), fmaxf(c_,d));
  pavg[gid] = 0.25f*(a+b_+c_+d);
}

// pointwise 16->16 (no bias) at half resolution
__global__ void k_pw16(const float* __restrict__ in, const float* __restrict__ w,
                       float* __restrict__ out){
  int gid = blockIdx.x*256 + threadIdx.x;
  if (gid >= NB*NCR*NL2) return;
  int p = gid & (NL2-1); int t = gid >> 12; int oc = t & 15; int bb = t >> 4;
  const float* xi = in + (size_t)bb*NCR*NL2 + p;
  float s = 0.f;
  #pragma unroll
  for (int ic=0; ic<NCR; ++ic) s += xi[(size_t)ic*NL2] * w[oc*NCR+ic];
  out[gid] = s;
}

// depthwise KxK pad P with bias, 64x64
__global__ void k_dw(const float* __restrict__ in, const float* __restrict__ w,
                     const float* __restrict__ bias, float* __restrict__ out,
                     int K, int P){
  int gid = blockIdx.x*256 + threadIdx.x;
  if (gid >= NB*NCR*NL2) return;
  int p = gid & (NL2-1); int t = gid >> 12; int c = t & 15; int bb = t >> 4;
  int y = p >> 6, x = p & 63;
  const float* xi = in + (size_t)(bb*NCR + c)*NL2;
  float s = bias[c];
  for (int dy=0; dy<K; ++dy){
    int iy = y + dy - P;
    if ((unsigned)iy < 64u){
      for (int dx=0; dx<K; ++dx){
        int ix = x + dx - P;
        if ((unsigned)ix < 64u) s += xi[iy*64 + ix] * w[(c*K + dy)*K + dx];
      }
    }
  }
  out[gid] = s;
}

// bilinear align_corners 64->128, write into feats channel slice coff..coff+16
__global__ void k_up(const float* __restrict__ in, float* __restrict__ feats, int coff){
  int gid = blockIdx.x*256 + threadIdx.x;
  if (gid >= NB*NCR*NL) return;
  int p = gid & (NL-1); int t = gid >> 14; int c = t & 15; int bb = t >> 4;
  int y = p >> 7, x = p & 127;
  const float sc = 63.0f/127.0f;
  float fy = y*sc; int ly = (int)floorf(fy); int hy = min(ly+1, 63); fy -= (float)ly;
  float fx = x*sc; int lx = (int)floorf(fx); int hx = min(lx+1, 63); float gx = fx - (float)lx;
  const float* xi = in + (size_t)(bb*NCR + c)*NL2;
  float v0 = xi[ly*64+lx]*(1.f-fy) + xi[hy*64+lx]*fy;
  float v1 = xi[ly*64+hx]*(1.f-fy) + xi[hy*64+hx]*fy;
  float v  = v0*(1.f-gx) + v1*gx;
  feats[(size_t)bb*128*NL + (size_t)(coff+c)*NL + p] = v;
}

// ---------------- CALayer ----------------
__global__ void k_camean(const float* __restrict__ x, float* __restrict__ cay){
  __shared__ float red[256];
  int bc = blockIdx.x; int tid = threadIdx.x;
  float s = 0.f;
  for (int i = tid; i < NL; i += 256) s += x[(size_t)bc*NL + i];
  red[tid] = s; __syncthreads();
  for (int st=128; st>0; st>>=1){ if (tid<st) red[tid]+=red[tid+st]; __syncthreads(); }
  if (tid==0) cay[bc] = red[0] / (float)NL;
}

__global__ void k_camlp(const float* __restrict__ cay,
                        const float* __restrict__ w1, const float* __restrict__ b1,
                        const float* __restrict__ w2, const float* __restrict__ b2,
                        float* __restrict__ cas){
  __shared__ float z[NB*4];
  int tid = threadIdx.x;
  if (tid < NB*4){
    int bb = tid >> 2, j = tid & 3;
    float s = b1[j];
    for (int ic=0; ic<NC; ++ic) s += cay[bb*NC+ic]*w1[j*NC+ic];
    z[tid] = fmaxf(s, 0.f);
  }
  __syncthreads();
  if (tid < NB*NC){
    int bb = tid >> 6, oc = tid & 63;
    float s = b2[oc];
    #pragma unroll
    for (int j=0; j<4; ++j) s += z[bb*4+j]*w2[oc*4+j];
    cas[tid] = sigmoidf_(s);
  }
}

// pre = x*sigmoid(fusion(feats)) + resid(x) + x*ca
__global__ void k_premask(const float* __restrict__ x, const float* __restrict__ feats,
                          const float* __restrict__ fw, const float* __restrict__ fb,
                          const float* __restrict__ rw, const float* __restrict__ rb,
                          const float* __restrict__ cas, float* __restrict__ pre){
  int gid = blockIdx.x*256 + threadIdx.x;
  if (gid >= NB*NC*NL) return;
  int p = gid & (NL-1); int t = gid >> 14; int c = t & 63; int bb = t >> 6;
  const float* fi = feats + (size_t)bb*128*NL + p;
  float a = fb[c];
  #pragma unroll 4
  for (int k=0; k<128; ++k) a += fi[(size_t)k*NL]*fw[c*128+k];
  float attn = sigmoidf_(a);
  const float* xi = x + (size_t)bb*NC*NL + p;
  float r = rb[c];
  #pragma unroll 4
  for (int ic=0; ic<NC; ++ic) r += xi[(size_t)ic*NL]*rw[c*NC+ic];
  float xv = x[gid];
  pre[gid] = xv*attn + r + xv*cas[bb*NC+c];
}

// mask = conv1x1(pre) + b + x
__global__ void k_mask(const float* __restrict__ pre, const float* __restrict__ w,
                       const float* __restrict__ b, const float* __restrict__ x,
                       float* __restrict__ mask){
  int gid = blockIdx.x*256 + threadIdx.x;
  if (gid >= NB*NC*NL) return;
  int p = gid & (NL-1); int t = gid >> 14; int c = t & 63; int bb = t >> 6;
  const float* xi = pre + (size_t)bb*NC*NL + p;
  float s = b[c];
  #pragma unroll 4
  for (int ic=0; ic<NC; ++ic) s += xi[(size_t)ic*NL]*w[c*NC+ic];
  mask[gid] = s + x[gid];
}

// ---------------- sparse attention ----------------

// xe [B,L,16] and normalized xen
__global__ void k_xe(const float* __restrict__ mask, const float* __restrict__ w,
                     const float* __restrict__ b, float* __restrict__ xe,
                     float* __restrict__ xen){
  int gid = blockIdx.x*256 + threadIdx.x;
  if (gid >= NB*NL) return;
  int bb = gid >> 14; int l = gid & (NL-1);
  const float* mi = mask + (size_t)bb*NC*NL + l;
  float v[16];
  #pragma unroll
  for (int oc=0; oc<NCR; ++oc){
    float s = b[oc];
    #pragma unroll 4
    for (int ic=0; ic<NC; ++ic) s += mi[(size_t)ic*NL]*w[oc*NC+ic];
    v[oc] = s;
  }
  float n2 = 0.f;
  #pragma unroll
  for (int oc=0; oc<NCR; ++oc) n2 += v[oc]*v[oc];
  float inv = 1.0f / fmaxf(sqrtf(n2), 5e-5f);
  float* xo = xe + (size_t)gid*NCR;
  float* no = xen + (size_t)gid*NCR;
  #pragma unroll
  for (int oc=0; oc<NCR; ++oc){ xo[oc] = v[oc]; no[oc] = v[oc]*inv; }
}

// ye [B,L,64]
__global__ void k_ye(const float* __restrict__ mask, const float* __restrict__ w,
                     const float* __restrict__ b, float* __restrict__ ye){
  int gid = blockIdx.x*256 + threadIdx.x;
  if (gid >= NB*NL*NC) return;
  int oc = gid & 63; int r = gid >> 6; int l = r & (NL-1); int bb = r >> 14;
  const float* mi = mask + (size_t)bb*NC*NL + l;
  float s = b[oc];
  #pragma unroll 4
  for (int ic=0; ic<NC; ++ic) s += mi[(size_t)ic*NL]*w[oc*NC+ic];
  ye[gid] = s;
}

// LSH codes: argmax over [rv, -rv], + h*32
__global__ void k_codes(const float* __restrict__ xe, const float* __restrict__ rot,
                        int* __restrict__ codes){
  int gid = blockIdx.x*256 + threadIdx.x;
  if (gid >= NB*NHASH*NL) return;
  int l = gid & (NL-1); int t = gid >> 14; int h = t & 3; int bb = t >> 2;
  const float* v = xe + (size_t)(bb*NL + l)*NCR;
  float q[16];
  #pragma unroll
  for (int f=0; f<16; ++f) q[f] = v[f];
  float rv[16];
  #pragma unroll
  for (int i=0; i<16; ++i){
    float s = 0.f;
    #pragma unroll
    for (int f=0; f<16; ++f) s += q[f]*rot[(f*NHASH + h)*16 + i];
    rv[i] = s;
  }
  float best = -1e30f; int bi = 0;
  #pragma unroll
  for (int i=0; i<16; ++i){ if (rv[i] > best){ best = rv[i]; bi = i; } }
  #pragma unroll
  for (int i=0; i<16; ++i){ float val = -rv[i]; if (val > best){ best = val; bi = 16+i; } }
  codes[gid] = bi + h*32;
}

__global__ void k_zero(int* __restrict__ p, int n){
  int i = blockIdx.x*256 + threadIdx.x;
  if (i < n) p[i] = 0;
}

// per-tile histogram: hist[b][key][tile]
__global__ void k_hist(const int* __restrict__ codes, int* __restrict__ hist){
  __shared__ int h[NKEY];
  int bt = blockIdx.x; int bb = bt >> 8; int tile = bt & 255;
  int tid = threadIdx.x;  // 128 threads
  h[tid] = 0; __syncthreads();
  for (int i = tid; i < TILESZ; i += 128)
    atomicAdd(&h[codes[bb*TOT + tile*TILESZ + i]], 1);
  __syncthreads();
  hist[bb*NKEY*NTILE + tid*NTILE + tile] = h[tid];
}

// exclusive scan over [key*NTILE + tile], per batch
__global__ void k_scan(const int* __restrict__ hist, int* __restrict__ offs){
  __shared__ int part[256];
  int bb = blockIdx.x; int t = threadIdx.x;  // 256 threads, 128 elems each
  const int* hi = hist + (size_t)bb*NKEY*NTILE;
  int* oo = offs + (size_t)bb*NKEY*NTILE;
  int s = 0;
  for (int i=0; i<128; ++i) s += hi[t*128 + i];
  part[t] = s; __syncthreads();
  if (t == 0){ int acc = 0; for (int i=0;i<256;++i){ int v=part[i]; part[i]=acc; acc+=v; } }
  __syncthreads();
  int run = part[t];
  for (int i=0; i<128; ++i){ int v = hi[t*128+i]; oo[t*128+i] = run; run += v; }
}

// stable scatter: one serial lane per tile
__global__ void k_scatter(const int* __restrict__ codes, const int* __restrict__ offs,
                          int* __restrict__ idx, int* __restrict__ undo){
  __shared__ int cnt[NKEY];
  int tid = threadIdx.x;  // 128 threads
  cnt[tid] = 0; __syncthreads();
  if (tid == 0){
    int bt = blockIdx.x; int bb = bt >> 8; int tile = bt & 255;
    const int* cb = codes + bb*TOT;
    const int* ob = offs + (size_t)bb*NKEY*NTILE;
    int* ib = idx + bb*TOT;
    int* ub = undo + bb*TOT;
    #pragma unroll 4
    for (int i=0; i<TILESZ; ++i){
      int j = tile*TILESZ + i;
      int k = cb[j];
      int pos = ob[k*NTILE + tile] + cnt[k]++;
      ib[pos] = j;
      ub[j] = pos;
    }
  }
}

// flash attention over 1536 keys (own/prev/next chunk), one row per thread
__global__ __launch_bounds__(512) void k_attn(const float* __restrict__ xe,
        const float* __restrict__ xen, const float* __restrict__ ye,
        const int* __restrict__ idx, float* __restrict__ ret, float* __restrict__ bsc){
  __shared__ float xm_t[128*16];
  __shared__ float y_t[128*64];
  __shared__ int   l_t[128];
  int blk = blockIdx.x;            // bb*128 + h*32 + kk
  int kk = blk & 31; int h = (blk >> 5) & 3; int bb = blk >> 7;
  int tid = threadIdx.x;
  const int* idxb = idx + bb*TOT;
  int pos_i = h*NL + kk*CHUNKSZ + tid;
  int li = idxb[pos_i] & (NL-1);
  const float* qp = xe + (size_t)(bb*NL + li)*NCR;
  float q[16];
  #pragma unroll
  for (int f=0; f<16; ++f) q[f] = qp[f];
  float m = -1e30f, ssum = 0.f;
  float acc[64];
  #pragma unroll
  for (int c=0; c<64; ++c) acc[c] = 0.f;
  for (int t=0; t<12; ++t){
    __syncthreads();
    if (tid < 128){
      int jj = t*128 + tid;
      int sec = jj >> 9; int j0 = jj & 511;
      int cc = kk + ((sec==1) ? -1 : (sec==2) ? 1 : 0);
      cc = (cc + NCHUNKS) & (NCHUNKS-1);
      l_t[tid] = idxb[h*NL + cc*CHUNKSZ + j0] & (NL-1);
    }
    __syncthreads();
    for (int f = tid; f < 128*16; f += 512){
      int r = f >> 4, c = f & 15;
      xm_t[f] = xen[(size_t)(bb*NL + l_t[r])*NCR + c];
    }
    for (int f = tid; f < 128*64; f += 512){
      int r = f >> 6, c = f & 63;
      y_t[f] = ye[(size_t)(bb*NL + l_t[r])*NC + c];
    }
    __syncthreads();
    for (int j=0; j<128; ++j){
      const float* xm = &xm_t[j*16];
      float s = 0.f;
      #pragma unroll
      for (int f=0; f<16; ++f) s += q[f]*xm[f];
      const float* yy = &y_t[j*64];
      if (s <= m){
        float w = __expf(s - m);
        ssum += w;
        #pragma unroll
        for (int c=0; c<64; ++c) acc[c] += w*yy[c];
      } else {
        float sc = __expf(m - s);
        m = s;
        ssum = ssum*sc + 1.0f;
        #pragma unroll
        for (int c=0; c<64; ++c) acc[c] = acc[c]*sc + yy[c];
      }
    }
  }
  float inv = 1.0f/ssum;
  float* ro = ret + (size_t)(bb*TOT + pos_i)*NC;
  #pragma unroll
  for (int c=0; c<64; ++c) ro[c] = acc[c]*inv;
  bsc[bb*TOT + pos_i] = m + logf(ssum);
}

// unsort + per-hash softmax combine + residual: fea[b,c,l]
__global__ void k_combine(const float* __restrict__ ret, const float* __restrict__ bsc,
                          const int* __restrict__ undo, const float* __restrict__ mask,
                          float* __restrict__ fea){
  int gid = blockIdx.x*256 + threadIdx.x;
  if (gid >= NB*NL) return;
  int bb = gid >> 14; int l = gid & (NL-1);
  const int* ub = undo + bb*TOT;
  int pos[4]; float sc[4];
  #pragma unroll
  for (int h=0; h<4; ++h){ pos[h] = ub[h*NL + l]; sc[h] = bsc[bb*TOT + pos[h]]; }
  float mx = fmaxf(fmaxf(sc[0],sc[1]), fmaxf(sc[2],sc[3]));
  float e[4]; float tot = 0.f;
  #pragma unroll
  for (int h=0; h<4; ++h){ e[h] = __expf(sc[h]-mx); tot += e[h]; }
  float inv = 0.1f/tot;   // includes RES_SCALE
  const float* mb_ = mask + (size_t)bb*NC*NL + l;
  float* fo = fea + (size_t)bb*NC*NL + l;
  const float* r0 = ret + (size_t)(bb*TOT + pos[0])*NC;
  const float* r1 = ret + (size_t)(bb*TOT + pos[1])*NC;
  const float* r2 = ret + (size_t)(bb*TOT + pos[2])*NC;
  const float* r3 = ret + (size_t)(bb*TOT + pos[3])*NC;
  #pragma unroll 4
  for (int c=0; c<64; ++c){
    float v = r0[c]*e[0] + r1[c]*e[1] + r2[c]*e[2] + r3[c]*e[3];
    fo[(size_t)c*NL] = v*inv + mb_[(size_t)c*NL];
  }
}

// out = conv1x1(fea, collect) + b + x
__global__ void k_collect(const float* __restrict__ fea, const float* __restrict__ w,
                          const float* __restrict__ b, const float* __restrict__ x,
                          float* __restrict__ out){
  int gid = blockIdx.x*256 + threadIdx.x;
  if (gid >= NB*NC*NL) return;
  int p = gid & (NL-1); int t = gid >> 14; int c = t & 63; int bb = t >> 6;
  const float* fi = fea + (size_t)bb*NC*NL + p;
  float s = b[c];
  #pragma unroll 4
  for (int ic=0; ic<NC; ++ic) s += fi[(size_t)ic*NL]*w[c*NC+ic];
  out[gid] = s + x[gid];
}

// ---------------- launcher ----------------
extern "C" void kernel_launch(void* const* d_in, const int* in_sizes, int n_in,
                              void* d_out, int out_size, void* d_ws, size_t ws_size,
                              hipStream_t stream) {
  const float* x        = (const float*)d_in[0];
  const float* spa_dw   = (const float*)d_in[1];
  const float* spa_db   = (const float*)d_in[2];
  const float* s0_pw    = (const float*)d_in[3];
  const float* s0_dww   = (const float*)d_in[4];
  const float* s0_dwb   = (const float*)d_in[5];
  const float* br_pw[3] = {(const float*)d_in[6], (const float*)d_in[9],  (const float*)d_in[12]};
  const float* br_dw[3] = {(const float*)d_in[7], (const float*)d_in[10], (const float*)d_in[13]};
  const float* br_db[3] = {(const float*)d_in[8], (const float*)d_in[11], (const float*)d_in[14]};
  const float* fus_w    = (const float*)d_in[15];
  const float* fus_b    = (const float*)d_in[16];
  const float* res_w    = (const float*)d_in[17];
  const float* res_b    = (const float*)d_in[18];
  const float* ca_w1    = (const float*)d_in[19];
  const float* ca_b1    = (const float*)d_in[20];
  const float* ca_w2    = (const float*)d_in[21];
  const float* ca_b2    = (const float*)d_in[22];
  const float* c11_w    = (const float*)d_in[23];
  const float* c11_b    = (const float*)d_in[24];
  const float* match_w  = (const float*)d_in[25];
  const float* match_b  = (const float*)d_in[26];
  const float* asm_w    = (const float*)d_in[27];
  const float* asm_b    = (const float*)d_in[28];
  const float* rot      = (const float*)d_in[29];
  const float* col_w    = (const float*)d_in[30];
  const float* col_b    = (const float*)d_in[31];
  float* out = (float*)d_out;

  float* ws   = (float*)d_ws;
  float* mask = ws + OFF_MASK;
  float* fea  = ws + OFF_FEA;
  float* xe   = ws + OFF_XE;
  float* xen  = ws + OFF_XEN;
  float* ye   = ws + OFF_YE;
  float* ret  = ws + OFF_RET;
  float* bsc  = ws + OFF_BSC;
  int*   ib   = (int*)(ws + OFF_INT);
  int* codes  = ib + IOFF_CODES;
  int* idx    = ib + IOFF_IDX;
  int* undo   = ib + IOFF_UNDO;
  int* hist   = ib + IOFF_HIST;
  int* offs   = ib + IOFF_OFFS;
  float* cay  = ws + OFF_CAY;
  float* cas  = ws + OFF_CAS;
  // phase-1 overlay (inside ret region)
  float* xr    = ws + OFF_XR;
  float* feats = ws + OFF_FEATS;
  float* pmx   = ws + OFF_PMX;
  float* pav   = ws + OFF_PAV;
  float* ptmp  = ws + OFF_PTMP;
  float* dwt   = ws + OFF_DWT;
  float* pre   = ws + OFF_PRE;

  // ---- phase 1: spatial attention ----
  k_xr<<<(NB*NCR*NL)/256, 256, 0, stream>>>(x, spa_dw, spa_db, xr);
  k_s0<<<(NB*32*NL)/256, 256, 0, stream>>>(xr, s0_pw, s0_dww, s0_dwb, feats);
  k_pool<<<(NB*NCR*NL2)/256, 256, 0, stream>>>(xr, pmx, pav);
  const int Ks[3] = {3,5,7}; const int Ps[3] = {1,2,3}; const int coffs[3] = {32,64,96};
  for (int br=0; br<3; ++br){
    k_pw16<<<(NB*NCR*NL2)/256, 256, 0, stream>>>(pmx, br_pw[br], ptmp);
    k_dw<<<(NB*NCR*NL2)/256, 256, 0, stream>>>(ptmp, br_dw[br], br_db[br], dwt, Ks[br], Ps[br]);
    k_up<<<(NB*NCR*NL)/256, 256, 0, stream>>>(dwt, feats, coffs[br]);
    k_pw16<<<(NB*NCR*NL2)/256, 256, 0, stream>>>(pav, br_pw[br], ptmp);
    k_dw<<<(NB*NCR*NL2)/256, 256, 0, stream>>>(ptmp, br_dw[br], br_db[br], dwt, Ks[br], Ps[br]);
    k_up<<<(NB*NCR*NL)/256, 256, 0, stream>>>(dwt, feats, coffs[br]+16);
  }
  k_camean<<<NB*NC, 256, 0, stream>>>(x, cay);
  k_camlp<<<1, 128, 0, stream>>>(cay, ca_w1, ca_b1, ca_w2, ca_b2, cas);
  k_premask<<<(NB*NC*NL)/256, 256, 0, stream>>>(x, feats, fus_w, fus_b, res_w, res_b, cas, pre);
  k_mask<<<(NB*NC*NL)/256, 256, 0, stream>>>(pre, c11_w, c11_b, x, mask);

  // ---- phase 2: sparse attention ----
  k_xe<<<(NB*NL)/256, 256, 0, stream>>>(mask, match_w, match_b, xe, xen);
  k_ye<<<(NB*NL*NC)/256, 256, 0, stream>>>(mask, asm_w, asm_b, ye);
  k_codes<<<(NB*NHASH*NL)/256, 256, 0, stream>>>(xe, rot, codes);
  k_zero<<<(NB*NKEY*NTILE + 255)/256, 256, 0, stream>>>(hist, NB*NKEY*NTILE);
  k_hist<<<NB*NTILE, 128, 0, stream>>>(codes, hist);
  k_scan<<<NB, 256, 0, stream>>>(hist, offs);
  k_scatter<<<NB*NTILE, 128, 0, stream>>>(codes, offs, idx, undo);
  k_attn<<<NB*NHASH*NCHUNKS, 512, 0, stream>>>(xe, xen, ye, idx, ret, bsc);
  k_combine<<<(NB*NL)/256, 256, 0, stream>>>(ret, bsc, undo, mask, fea);
  k_collect<<<(NB*NC*NL)/256, 256, 0, stream>>>(fea, col_w, col_b, x, out);
}

// Round 2
// 1076.386 us; speedup vs baseline: 1.0947x; 1.0947x over previous
//
#include <hip/hip_runtime.h>
#include <math.h>

// ---------------- problem constants ----------------
static constexpr int NB = 2;
static constexpr int NC = 64;
static constexpr int NHp = 128, NWp = 128;
static constexpr int NL = NHp * NWp;     // 16384
static constexpr int NCR = 16;
static constexpr int NL2 = 64 * 64;      // 4096
static constexpr int NHASH = 4;
static constexpr int CHUNKSZ = 512;
static constexpr int NCHUNKS = 32;
static constexpr int TOT = NHASH * NL;   // 65536
static constexpr int NKEY = 128;
static constexpr int NTILE = 256;
static constexpr int TILESZ = TOT / NTILE; // 256

typedef _Float16 half4 __attribute__((ext_vector_type(4)));
typedef _Float16 half8 __attribute__((ext_vector_type(8)));
typedef float f32x4 __attribute__((ext_vector_type(4)));

// ---------------- workspace layout (float units) ----------------
static constexpr size_t OFF_MASK = 0;                                   // 2,097,152
static constexpr size_t OFF_FEA  = OFF_MASK + (size_t)NB*NC*NL;         // 2,097,152 (also pre1 overlay)
static constexpr size_t OFF_XE   = OFF_FEA  + (size_t)NB*NC*NL;         // 4,194,304 fp32 [B*L][16]
static constexpr size_t OFF_XEH  = OFF_XE   + (size_t)NB*NL*NCR;        // 4,718,592 half [B*L][16]
static constexpr size_t OFF_XENH = OFF_XEH  + (size_t)NB*NL*NCR/2;      // 4,980,736 half
static constexpr size_t OFF_YEH  = OFF_XENH + (size_t)NB*NL*NCR/2;      // 5,242,880 half [B*L][64]
static constexpr size_t OFF_RET  = OFF_YEH  + (size_t)NB*NL*NC/2;       // 6,291,456 half [B*TOT][64]
static constexpr size_t OFF_BSC  = OFF_RET  + (size_t)NB*TOT*NC/2;      // 10,485,760
static constexpr size_t OFF_INT  = OFF_BSC  + (size_t)NB*TOT;           // 10,616,832
static constexpr size_t IOFF_CODES = 0;
static constexpr size_t IOFF_IDX   = IOFF_CODES + (size_t)NB*TOT;
static constexpr size_t IOFF_UNDO  = IOFF_IDX   + (size_t)NB*TOT;
static constexpr size_t IOFF_HIST  = IOFF_UNDO  + (size_t)NB*TOT;
static constexpr size_t IOFF_OFFS  = IOFF_HIST  + (size_t)NB*NKEY*NTILE/2;
static constexpr size_t IOFF_END   = IOFF_OFFS  + (size_t)NB*NKEY*NTILE/2;
static constexpr size_t OFF_CAY = OFF_INT + IOFF_END;
static constexpr size_t OFF_CAS = OFF_CAY + 128;
static constexpr size_t OFF_CRW = OFF_CAS + 128;
static constexpr size_t OFF_CRB = OFF_CRW + 4096;
static constexpr size_t OFF_END = OFF_CRB + 64;
// phase-1 overlay: lives in [OFF_XE, ...) which is written only in phase 2
static constexpr size_t OFF_XR    = OFF_XE;                             // 524,288
static constexpr size_t OFF_FEATS = OFF_XR    + (size_t)NB*NCR*NL;      // 4,194,304 floats
static constexpr size_t OFF_PMX   = OFF_FEATS + (size_t)NB*8*NCR*NL;
static constexpr size_t OFF_PAV   = OFF_PMX   + (size_t)NB*NCR*NL2;
static constexpr size_t OFF_PTMP  = OFF_PAV   + (size_t)NB*NCR*NL2;
static constexpr size_t OFF_DWT   = OFF_PTMP  + (size_t)NB*NCR*NL2;
static constexpr size_t OFF_PRE1  = OFF_FEA;                            // overlay in fea region
static_assert(OFF_DWT + (size_t)NB*NCR*NL2 <= OFF_BSC, "overlay fits");

__device__ __forceinline__ float sigmoidf_(float v){ return 1.0f/(1.0f + expf(-v)); }

// ---------------- phase 1 ----------------

// xr = conv1x1(x, 64->16): one thread per (b,p), input row in regs
__global__ void k_xr(const float* __restrict__ x, const float* __restrict__ w,
                     const float* __restrict__ b, float* __restrict__ xr){
  int gid = blockIdx.x*256 + threadIdx.x;
  if (gid >= NB*NL) return;
  int bb = gid >> 14, p = gid & (NL-1);
  const float* xi = x + (size_t)bb*NC*NL + p;
  float r[64];
  #pragma unroll
  for (int ic=0; ic<64; ++ic) r[ic] = xi[(size_t)ic*NL];
  float* xo = xr + (size_t)bb*NCR*NL + p;
  for (int oc=0; oc<16; ++oc){
    float s = b[oc];
    const float* wr = w + oc*64;
    #pragma unroll
    for (int ic=0; ic<64; ++ic) s += r[ic]*wr[ic];
    xo[(size_t)oc*NL] = s;
  }
}

__global__ void k_s0(const float* __restrict__ xr, const float* __restrict__ pw,
                     const float* __restrict__ dww, const float* __restrict__ dwb,
                     float* __restrict__ feats){
  int gid = blockIdx.x*256 + threadIdx.x;
  if (gid >= NB*NL) return;
  int bb = gid >> 14, p = gid & (NL-1);
  const float* xi = xr + (size_t)bb*NCR*NL + p;
  float r[16];
  #pragma unroll
  for (int ic=0; ic<16; ++ic) r[ic] = xi[(size_t)ic*NL];
  float* fo = feats + (size_t)bb*128*NL + p;
  for (int oc=0; oc<32; ++oc){
    float s = 0.f;
    #pragma unroll
    for (int ic=0; ic<16; ++ic) s += r[ic]*pw[oc*16+ic];
    fo[(size_t)oc*NL] = s*dww[oc] + dwb[oc];
  }
}

__global__ void k_pool(const float* __restrict__ xr, float* __restrict__ pmax,
                       float* __restrict__ pavg){
  int gid = blockIdx.x*256 + threadIdx.x;
  if (gid >= NB*NCR*NL2) return;
  int p = gid & (NL2-1); int t = gid >> 12; int c = t & 15; int bb = t >> 4;
  int y = p >> 6, x2 = p & 63;
  const float* base = xr + (size_t)(bb*NCR + c)*NL + (size_t)(2*y)*NWp + 2*x2;
  float a = base[0], b_ = base[1], c_ = base[NWp], d = base[NWp+1];
  pmax[gid] = fmaxf(fmaxf(a,b_), fmaxf(c_,d));
  pavg[gid] = 0.25f*(a+b_+c_+d);
}

__global__ void k_pw16(const float* __restrict__ in, const float* __restrict__ w,
                       float* __restrict__ out){
  int gid = blockIdx.x*256 + threadIdx.x;
  if (gid >= NB*NCR*NL2) return;
  int p = gid & (NL2-1); int t = gid >> 12; int oc = t & 15; int bb = t >> 4;
  const float* xi = in + (size_t)bb*NCR*NL2 + p;
  float s = 0.f;
  #pragma unroll
  for (int ic=0; ic<NCR; ++ic) s += xi[(size_t)ic*NL2] * w[oc*NCR+ic];
  out[gid] = s;
}

__global__ void k_dw(const float* __restrict__ in, const float* __restrict__ w,
                     const float* __restrict__ bias, float* __restrict__ out,
                     int K, int P){
  int gid = blockIdx.x*256 + threadIdx.x;
  if (gid >= NB*NCR*NL2) return;
  int p = gid & (NL2-1); int t = gid >> 12; int c = t & 15; int bb = t >> 4;
  int y = p >> 6, x = p & 63;
  const float* xi = in + (size_t)(bb*NCR + c)*NL2;
  float s = bias[c];
  for (int dy=0; dy<K; ++dy){
    int iy = y + dy - P;
    if ((unsigned)iy < 64u){
      for (int dx=0; dx<K; ++dx){
        int ix = x + dx - P;
        if ((unsigned)ix < 64u) s += xi[iy*64 + ix] * w[(c*K + dy)*K + dx];
      }
    }
  }
  out[gid] = s;
}

__global__ void k_up(const float* __restrict__ in, float* __restrict__ feats, int coff){
  int gid = blockIdx.x*256 + threadIdx.x;
  if (gid >= NB*NCR*NL) return;
  int p = gid & (NL-1); int t = gid >> 14; int c = t & 15; int bb = t >> 4;
  int y = p >> 7, x = p & 127;
  const float sc = 63.0f/127.0f;
  float fy = y*sc; int ly = (int)floorf(fy); int hy = min(ly+1, 63); fy -= (float)ly;
  float fx = x*sc; int lx = (int)floorf(fx); int hx = min(lx+1, 63); float gx = fx - (float)lx;
  const float* xi = in + (size_t)(bb*NCR + c)*NL2;
  float v0 = xi[ly*64+lx]*(1.f-fy) + xi[hy*64+lx]*fy;
  float v1 = xi[ly*64+hx]*(1.f-fy) + xi[hy*64+hx]*fy;
  feats[(size_t)bb*128*NL + (size_t)(coff+c)*NL + p] = v0*(1.f-gx) + v1*gx;
}

__global__ void k_camean(const float* __restrict__ x, float* __restrict__ cay){
  __shared__ float red[256];
  int bc = blockIdx.x; int tid = threadIdx.x;
  float s = 0.f;
  for (int i = tid; i < NL; i += 256) s += x[(size_t)bc*NL + i];
  red[tid] = s; __syncthreads();
  for (int st=128; st>0; st>>=1){ if (tid<st) red[tid]+=red[tid+st]; __syncthreads(); }
  if (tid==0) cay[bc] = red[0] / (float)NL;
}

__global__ void k_camlp(const float* __restrict__ cay,
                        const float* __restrict__ w1, const float* __restrict__ b1,
                        const float* __restrict__ w2, const float* __restrict__ b2,
                        float* __restrict__ cas){
  __shared__ float z[NB*4];
  int tid = threadIdx.x;
  if (tid < NB*4){
    int bb = tid >> 2, j = tid & 3;
    float s = b1[j];
    for (int ic=0; ic<NC; ++ic) s += cay[bb*NC+ic]*w1[j*NC+ic];
    z[tid] = fmaxf(s, 0.f);
  }
  __syncthreads();
  if (tid < NB*NC){
    int bb = tid >> 6, oc = tid & 63;
    float s = b2[oc];
    #pragma unroll
    for (int j=0; j<4; ++j) s += z[bb*4+j]*w2[oc*4+j];
    cas[tid] = sigmoidf_(s);
  }
}

// crw = c11w @ rw ; crb = c11b + c11w @ rb
__global__ void k_wprod(const float* __restrict__ c11w, const float* __restrict__ c11b,
                        const float* __restrict__ rw, const float* __restrict__ rb,
                        float* __restrict__ crw, float* __restrict__ crb){
  int gid = blockIdx.x*256 + threadIdx.x;
  if (gid >= 4096) return;
  int o = gid >> 6, i = gid & 63;
  float s = 0.f;
  for (int k=0; k<64; ++k) s += c11w[o*64+k]*rw[k*64+i];
  crw[gid] = s;
  if (i == 0){
    float t = c11b[o];
    for (int k=0; k<64; ++k) t += c11w[o*64+k]*rb[k];
    crb[o] = t;
  }
}

// pre1 = x*(sigmoid(fusion(feats)) + ca) ; oc split into halves across blocks
__global__ void k_attnmul(const float* __restrict__ x, const float* __restrict__ feats,
                          const float* __restrict__ fw, const float* __restrict__ fb,
                          const float* __restrict__ cas, float* __restrict__ pre1){
  int bp = blockIdx.x >> 1, half = blockIdx.x & 1;
  int gid = bp*256 + threadIdx.x;
  if (gid >= NB*NL) return;
  int bb = gid >> 14, p = gid & (NL-1);
  const float* fi = feats + (size_t)bb*128*NL + p;
  float fr[128];
  #pragma unroll
  for (int k=0; k<128; ++k) fr[k] = fi[(size_t)k*NL];
  const float* xb = x + (size_t)bb*NC*NL + p;
  float* po = pre1 + (size_t)bb*NC*NL + p;
  int oc0 = half*32;
  for (int oc=oc0; oc<oc0+32; ++oc){
    float s = fb[oc];
    const float* wr = fw + oc*128;
    #pragma unroll
    for (int k=0; k<128; ++k) s += fr[k]*wr[k];
    float xv = xb[(size_t)oc*NL];
    po[(size_t)oc*NL] = xv*(sigmoidf_(s) + cas[bb*64+oc]);
  }
}

// mask = conv1x1(pre1) + crw@x + crb + x
__global__ void k_mask(const float* __restrict__ pre1, const float* __restrict__ c11w,
                       const float* __restrict__ crw, const float* __restrict__ crb,
                       const float* __restrict__ x, float* __restrict__ mask){
  int bp = blockIdx.x >> 1, half = blockIdx.x & 1;
  int gid = bp*256 + threadIdx.x;
  if (gid >= NB*NL) return;
  int bb = gid >> 14, p = gid & (NL-1);
  const float* pi = pre1 + (size_t)bb*NC*NL + p;
  const float* xi = x + (size_t)bb*NC*NL + p;
  float pr[64], xr_[64];
  #pragma unroll
  for (int ic=0; ic<64; ++ic){ pr[ic] = pi[(size_t)ic*NL]; xr_[ic] = xi[(size_t)ic*NL]; }
  float* mo = mask + (size_t)bb*NC*NL + p;
  int oc0 = half*32;
  for (int oc=oc0; oc<oc0+32; ++oc){
    float s = crb[oc];
    const float* w1 = c11w + oc*64;
    const float* w2 = crw + oc*64;
    #pragma unroll
    for (int ic=0; ic<64; ++ic) s += pr[ic]*w1[ic] + xr_[ic]*w2[ic];
    mo[(size_t)oc*NL] = s + xr_[oc];
  }
}

// ---------------- phase 2 ----------------

// xe fp32 (for codes) + xe half (Q) + normalized xe half (K)
__global__ void k_xe(const float* __restrict__ mask, const float* __restrict__ w,
                     const float* __restrict__ b, float* __restrict__ xe,
                     _Float16* __restrict__ xeh, _Float16* __restrict__ xenh){
  int gid = blockIdx.x*256 + threadIdx.x;
  if (gid >= NB*NL) return;
  int bb = gid >> 14; int l = gid & (NL-1);
  const float* mi = mask + (size_t)bb*NC*NL + l;
  float r[64];
  #pragma unroll
  for (int ic=0; ic<64; ++ic) r[ic] = mi[(size_t)ic*NL];
  float v[16]; float n2 = 0.f;
  for (int oc=0; oc<16; ++oc){
    float s = b[oc];
    const float* wr = w + oc*64;
    #pragma unroll
    for (int ic=0; ic<64; ++ic) s += r[ic]*wr[ic];
    v[oc] = s; n2 += s*s;
  }
  float inv = 1.0f / fmaxf(sqrtf(n2), 5e-5f);
  float* xo = xe + (size_t)gid*NCR;
  _Float16* ho = xeh + (size_t)gid*NCR;
  _Float16* no = xenh + (size_t)gid*NCR;
  #pragma unroll
  for (int oc=0; oc<16; ++oc){
    xo[oc] = v[oc];
    ho[oc] = (_Float16)v[oc];
    no[oc] = (_Float16)(v[oc]*inv);
  }
}

// ye in half [B*L][64]
__global__ void k_yeh(const float* __restrict__ mask, const float* __restrict__ w,
                      const float* __restrict__ b, _Float16* __restrict__ yeh){
  int gid = blockIdx.x*256 + threadIdx.x;
  if (gid >= NB*NL) return;
  int bb = gid >> 14; int l = gid & (NL-1);
  const float* mi = mask + (size_t)bb*NC*NL + l;
  float r[64];
  #pragma unroll
  for (int ic=0; ic<64; ++ic) r[ic] = mi[(size_t)ic*NL];
  _Float16* yo = yeh + (size_t)gid*NC;
  for (int oc=0; oc<64; ++oc){
    float s = b[oc];
    const float* wr = w + oc*64;
    #pragma unroll
    for (int ic=0; ic<64; ++ic) s += r[ic]*wr[ic];
    yo[oc] = (_Float16)s;
  }
}

__global__ void k_codes(const float* __restrict__ xe, const float* __restrict__ rot,
                        int* __restrict__ codes){
  int gid = blockIdx.x*256 + threadIdx.x;
  if (gid >= NB*NHASH*NL) return;
  int l = gid & (NL-1); int t = gid >> 14; int h = t & 3; int bb = t >> 2;
  const float* v = xe + (size_t)(bb*NL + l)*NCR;
  float q[16];
  #pragma unroll
  for (int f=0; f<16; ++f) q[f] = v[f];
  float rv[16];
  #pragma unroll
  for (int i=0; i<16; ++i){
    float s = 0.f;
    #pragma unroll
    for (int f=0; f<16; ++f) s += q[f]*rot[(f*NHASH + h)*16 + i];
    rv[i] = s;
  }
  float best = -1e30f; int bi = 0;
  #pragma unroll
  for (int i=0; i<16; ++i){ if (rv[i] > best){ best = rv[i]; bi = i; } }
  #pragma unroll
  for (int i=0; i<16; ++i){ float val = -rv[i]; if (val > best){ best = val; bi = 16+i; } }
  codes[gid] = bi + h*32;
}

__global__ void k_zero(int* __restrict__ p, int n){
  int i = blockIdx.x*256 + threadIdx.x;
  if (i < n) p[i] = 0;
}

__global__ void k_hist(const int* __restrict__ codes, int* __restrict__ hist){
  __shared__ int h[NKEY];
  int bt = blockIdx.x; int bb = bt >> 8; int tile = bt & 255;
  int tid = threadIdx.x;
  h[tid] = 0; __syncthreads();
  for (int i = tid; i < TILESZ; i += 128)
    atomicAdd(&h[codes[bb*TOT + tile*TILESZ + i]], 1);
  __syncthreads();
  hist[bb*NKEY*NTILE + tid*NTILE + tile] = h[tid];
}

__global__ void k_scan(const int* __restrict__ hist, int* __restrict__ offs){
  __shared__ int part[256];
  int bb = blockIdx.x; int t = threadIdx.x;
  const int* hi = hist + (size_t)bb*NKEY*NTILE;
  int* oo = offs + (size_t)bb*NKEY*NTILE;
  int s = 0;
  for (int i=0; i<128; ++i) s += hi[t*128 + i];
  part[t] = s; __syncthreads();
  if (t == 0){ int acc = 0; for (int i=0;i<256;++i){ int v=part[i]; part[i]=acc; acc+=v; } }
  __syncthreads();
  int run = part[t];
  for (int i=0; i<128; ++i){ int v = hi[t*128+i]; oo[t*128+i] = run; run += v; }
}

__global__ void k_scatter(const int* __restrict__ codes, const int* __restrict__ offs,
                          int* __restrict__ idx, int* __restrict__ undo){
  __shared__ int cnt[NKEY];
  int tid = threadIdx.x;
  cnt[tid] = 0; __syncthreads();
  if (tid == 0){
    int bt = blockIdx.x; int bb = bt >> 8; int tile = bt & 255;
    const int* cb = codes + bb*TOT;
    const int* ob = offs + (size_t)bb*NKEY*NTILE;
    int* ib = idx + bb*TOT;
    int* ub = undo + bb*TOT;
    #pragma unroll 4
    for (int i=0; i<TILESZ; ++i){
      int j = tile*TILESZ + i;
      int k = cb[j];
      int pos = ob[k*NTILE + tile] + cnt[k]++;
      ib[pos] = j;
      ub[j] = pos;
    }
  }
}

// MFMA flash attention. grid = NB*NHASH*NCHUNKS blocks x 512 threads.
// Wave w owns queries w*64..w*64+63. Keys streamed in 24 tiles of 64.
__global__ __launch_bounds__(512) void k_attn(
    const _Float16* __restrict__ xeh, const _Float16* __restrict__ xenh,
    const _Float16* __restrict__ yeh, const int* __restrict__ idx,
    _Float16* __restrict__ retb, float* __restrict__ bsc){
  __shared__ _Float16 kt[64*24];    // K tile [key][16+pad8]
  __shared__ _Float16 vt[64*72];    // V^T tile [c][64+pad8]
  int blk = blockIdx.x;
  int kk = blk & 31; int h = (blk >> 5) & 3; int bb = blk >> 7;
  int tid = threadIdx.x;
  int w = tid >> 6, lane = tid & 63, col = lane & 15, grp = lane >> 4;
  const int* idxb = idx + bb*TOT;
  int qbase = h*NL + kk*CHUNKSZ + w*64;

  // Q fragments (loop-invariant): B operand, col=q, k=feat
  half4 qfr[4]; int posq[4];
  #pragma unroll
  for (int qf=0; qf<4; ++qf){
    posq[qf] = qbase + qf*16 + col;
    int lq = idxb[posq[qf]] & (NL-1);
    qfr[qf] = *(const half4*)(xeh + ((size_t)bb*NL + lq)*16 + grp*4);
  }

  f32x4 O[4][4];   // [cf][qf]
  #pragma unroll
  for (int a=0; a<4; ++a)
    #pragma unroll
    for (int b=0; b<4; ++b) O[a][b] = (f32x4){0.f,0.f,0.f,0.f};
  float m_[4] = {-1e30f,-1e30f,-1e30f,-1e30f};
  float ssum[4] = {0.f,0.f,0.f,0.f};

  for (int t=0; t<24; ++t){
    __syncthreads();
    // stage V^T: thread -> (key=tid&63, c0=(tid>>6)*8)
    {
      int kx = tid & 63, c0 = (tid >> 6) * 8;
      int jj = t*64 + kx; int sec = jj >> 9; int j0 = jj & 511;
      int cc = kk + ((sec==1) ? -1 : (sec==2) ? 1 : 0);
      cc = (cc + NCHUNKS) & (NCHUNKS-1);
      int lv = idxb[h*NL + cc*CHUNKSZ + j0] & (NL-1);
      half8 vv = *(const half8*)(yeh + ((size_t)bb*NL + lv)*64 + c0);
      #pragma unroll
      for (int j=0; j<8; ++j) vt[(c0+j)*72 + kx] = vv[j];
    }
    // stage K: threads 0..127 -> (row=tid>>1, half-row=tid&1)
    if (tid < 128){
      int r = tid >> 1, hf = tid & 1;
      int jj = t*64 + r; int sec = jj >> 9; int j0 = jj & 511;
      int cc = kk + ((sec==1) ? -1 : (sec==2) ? 1 : 0);
      cc = (cc + NCHUNKS) & (NCHUNKS-1);
      int lk = idxb[h*NL + cc*CHUNKSZ + j0] & (NL-1);
      *(half8*)(kt + r*24 + hf*8) =
          *(const half8*)(xenh + ((size_t)bb*NL + lk)*16 + hf*8);
    }
    __syncthreads();

    // scores: S[kb][qf] = K_frag x Q_frag  (D: col=q, row=key)
    f32x4 S[4][4];
    #pragma unroll
    for (int kb=0; kb<4; ++kb){
      half4 ka = *(const half4*)(kt + (kb*16 + col)*24 + grp*4);
      #pragma unroll
      for (int qf=0; qf<4; ++qf)
        S[kb][qf] = __builtin_amdgcn_mfma_f32_16x16x16f16(
            ka, qfr[qf], (f32x4){0.f,0.f,0.f,0.f}, 0, 0, 0);
    }

    // online softmax per qf; P frags reuse the D layout as B operand
    half4 pf[4][4];  // [qf][kb]
    #pragma unroll
    for (int qf=0; qf<4; ++qf){
      float mt = -1e30f;
      #pragma unroll
      for (int kb=0; kb<4; ++kb)
        #pragma unroll
        for (int i=0; i<4; ++i) mt = fmaxf(mt, S[kb][qf][i]);
      mt = fmaxf(mt, __shfl_xor(mt, 16, 64));
      mt = fmaxf(mt, __shfl_xor(mt, 32, 64));
      float mn = fmaxf(m_[qf], mt);
      float sc = __expf(m_[qf] - mn);
      float ps = 0.f;
      #pragma unroll
      for (int kb=0; kb<4; ++kb){
        #pragma unroll
        for (int i=0; i<4; ++i){
          float p = __expf(S[kb][qf][i] - mn);
          ps += p;
          pf[qf][kb][i] = (_Float16)p;
        }
      }
      ps += __shfl_xor(ps, 16, 64);
      ps += __shfl_xor(ps, 32, 64);
      ssum[qf] = ssum[qf]*sc + ps;
      m_[qf] = mn;
      #pragma unroll
      for (int cf=0; cf<4; ++cf)
        #pragma unroll
        for (int i=0; i<4; ++i) O[cf][qf][i] *= sc;
    }

    // PV: O[cf][qf] += V^T_frag(cf,kb) x P(qf,kb)
    #pragma unroll
    for (int cf=0; cf<4; ++cf){
      #pragma unroll
      for (int kb=0; kb<4; ++kb){
        half4 va = *(const half4*)(vt + (cf*16 + col)*72 + kb*16 + grp*4);
        #pragma unroll
        for (int qf=0; qf<4; ++qf)
          O[cf][qf] = __builtin_amdgcn_mfma_f32_16x16x16f16(
              va, pf[qf][kb], O[cf][qf], 0, 0, 0);
      }
    }
  }

  // epilogue
  #pragma unroll
  for (int qf=0; qf<4; ++qf){
    float inv = 1.0f/ssum[qf];
    size_t rb = ((size_t)bb*TOT + posq[qf])*64;
    #pragma unroll
    for (int cf=0; cf<4; ++cf){
      half4 o;
      #pragma unroll
      for (int i=0; i<4; ++i) o[i] = (_Float16)(O[cf][qf][i]*inv);
      *(half4*)(retb + rb + cf*16 + grp*4) = o;
    }
    if (grp == 0) bsc[(size_t)bb*TOT + posq[qf]] = m_[qf] + logf(ssum[qf]);
  }
}

__global__ void k_combine(const _Float16* __restrict__ retb, const float* __restrict__ bsc,
                          const int* __restrict__ undo, const float* __restrict__ mask,
                          float* __restrict__ fea){
  int gid = blockIdx.x*256 + threadIdx.x;
  if (gid >= NB*NL) return;
  int bb = gid >> 14; int l = gid & (NL-1);
  const int* ub = undo + bb*TOT;
  int pos[4]; float sc[4];
  #pragma unroll
  for (int h=0; h<4; ++h){ pos[h] = ub[h*NL + l]; sc[h] = bsc[bb*TOT + pos[h]]; }
  float mx = fmaxf(fmaxf(sc[0],sc[1]), fmaxf(sc[2],sc[3]));
  float e[4]; float tot = 0.f;
  #pragma unroll
  for (int h=0; h<4; ++h){ e[h] = __expf(sc[h]-mx); tot += e[h]; }
  float inv = 0.1f/tot;
  const float* mb_ = mask + (size_t)bb*NC*NL + l;
  float* fo = fea + (size_t)bb*NC*NL + l;
  const _Float16* r0 = retb + ((size_t)bb*TOT + pos[0])*NC;
  const _Float16* r1 = retb + ((size_t)bb*TOT + pos[1])*NC;
  const _Float16* r2 = retb + ((size_t)bb*TOT + pos[2])*NC;
  const _Float16* r3 = retb + ((size_t)bb*TOT + pos[3])*NC;
  #pragma unroll 4
  for (int c=0; c<64; ++c){
    float v = (float)r0[c]*e[0] + (float)r1[c]*e[1] + (float)r2[c]*e[2] + (float)r3[c]*e[3];
    fo[(size_t)c*NL] = v*inv + mb_[(size_t)c*NL];
  }
}

__global__ void k_collect(const float* __restrict__ fea, const float* __restrict__ w,
                          const float* __restrict__ b, const float* __restrict__ x,
                          float* __restrict__ out){
  int gid = blockIdx.x*256 + threadIdx.x;
  if (gid >= NB*NL) return;
  int bb = gid >> 14, p = gid & (NL-1);
  const float* fi = fea + (size_t)bb*NC*NL + p;
  const float* xi = x + (size_t)bb*NC*NL + p;
  float r[64];
  #pragma unroll
  for (int ic=0; ic<64; ++ic) r[ic] = fi[(size_t)ic*NL];
  float* oo = out + (size_t)bb*NC*NL + p;
  for (int oc=0; oc<64; ++oc){
    float s = b[oc];
    const float* wr = w + oc*64;
    #pragma unroll
    for (int ic=0; ic<64; ++ic) s += r[ic]*wr[ic];
    oo[(size_t)oc*NL] = s + xi[(size_t)oc*NL];
  }
}

// ---------------- launcher ----------------
extern "C" void kernel_launch(void* const* d_in, const int* in_sizes, int n_in,
                              void* d_out, int out_size, void* d_ws, size_t ws_size,
                              hipStream_t stream) {
  const float* x        = (const float*)d_in[0];
  const float* spa_dw   = (const float*)d_in[1];
  const float* spa_db   = (const float*)d_in[2];
  const float* s0_pw    = (const float*)d_in[3];
  const float* s0_dww   = (const float*)d_in[4];
  const float* s0_dwb   = (const float*)d_in[5];
  const float* br_pw[3] = {(const float*)d_in[6], (const float*)d_in[9],  (const float*)d_in[12]};
  const float* br_dw[3] = {(const float*)d_in[7], (const float*)d_in[10], (const float*)d_in[13]};
  const float* br_db[3] = {(const float*)d_in[8], (const float*)d_in[11], (const float*)d_in[14]};
  const float* fus_w    = (const float*)d_in[15];
  const float* fus_b    = (const float*)d_in[16];
  const float* res_w    = (const float*)d_in[17];
  const float* res_b    = (const float*)d_in[18];
  const float* ca_w1    = (const float*)d_in[19];
  const float* ca_b1    = (const float*)d_in[20];
  const float* ca_w2    = (const float*)d_in[21];
  const float* ca_b2    = (const float*)d_in[22];
  const float* c11_w    = (const float*)d_in[23];
  const float* c11_b    = (const float*)d_in[24];
  const float* match_w  = (const float*)d_in[25];
  const float* match_b  = (const float*)d_in[26];
  const float* asm_w    = (const float*)d_in[27];
  const float* asm_b    = (const float*)d_in[28];
  const float* rot      = (const float*)d_in[29];
  const float* col_w    = (const float*)d_in[30];
  const float* col_b    = (const float*)d_in[31];
  float* out = (float*)d_out;

  float* ws    = (float*)d_ws;
  float* mask  = ws + OFF_MASK;
  float* fea   = ws + OFF_FEA;
  float* xe    = ws + OFF_XE;
  _Float16* xeh  = (_Float16*)(ws + OFF_XEH);
  _Float16* xenh = (_Float16*)(ws + OFF_XENH);
  _Float16* yeh  = (_Float16*)(ws + OFF_YEH);
  _Float16* retb = (_Float16*)(ws + OFF_RET);
  float* bsc   = ws + OFF_BSC;
  int*   ib    = (int*)(ws + OFF_INT);
  int* codes   = ib + IOFF_CODES;
  int* idx     = ib + IOFF_IDX;
  int* undo    = ib + IOFF_UNDO;
  int* hist    = ib + IOFF_HIST;
  int* offs    = ib + IOFF_OFFS;
  float* cay   = ws + OFF_CAY;
  float* cas   = ws + OFF_CAS;
  float* crw   = ws + OFF_CRW;
  float* crb   = ws + OFF_CRB;
  float* xr    = ws + OFF_XR;
  float* feats = ws + OFF_FEATS;
  float* pmx   = ws + OFF_PMX;
  float* pav   = ws + OFF_PAV;
  float* ptmp  = ws + OFF_PTMP;
  float* dwt   = ws + OFF_DWT;
  float* pre1  = ws + OFF_PRE1;

  // ---- phase 1 ----
  k_xr<<<(NB*NL)/256, 256, 0, stream>>>(x, spa_dw, spa_db, xr);
  k_wprod<<<16, 256, 0, stream>>>(c11_w, c11_b, res_w, res_b, crw, crb);
  k_s0<<<(NB*NL)/256, 256, 0, stream>>>(xr, s0_pw, s0_dww, s0_dwb, feats);
  k_pool<<<(NB*NCR*NL2)/256, 256, 0, stream>>>(xr, pmx, pav);
  const int Ks[3] = {3,5,7}; const int Ps[3] = {1,2,3}; const int coffs[3] = {32,64,96};
  for (int br=0; br<3; ++br){
    k_pw16<<<(NB*NCR*NL2)/256, 256, 0, stream>>>(pmx, br_pw[br], ptmp);
    k_dw<<<(NB*NCR*NL2)/256, 256, 0, stream>>>(ptmp, br_dw[br], br_db[br], dwt, Ks[br], Ps[br]);
    k_up<<<(NB*NCR*NL)/256, 256, 0, stream>>>(dwt, feats, coffs[br]);
    k_pw16<<<(NB*NCR*NL2)/256, 256, 0, stream>>>(pav, br_pw[br], ptmp);
    k_dw<<<(NB*NCR*NL2)/256, 256, 0, stream>>>(ptmp, br_dw[br], br_db[br], dwt, Ks[br], Ps[br]);
    k_up<<<(NB*NCR*NL)/256, 256, 0, stream>>>(dwt, feats, coffs[br]+16);
  }
  k_camean<<<NB*NC, 256, 0, stream>>>(x, cay);
  k_camlp<<<1, 128, 0, stream>>>(cay, ca_w1, ca_b1, ca_w2, ca_b2, cas);
  k_attnmul<<<2*((NB*NL)/256), 256, 0, stream>>>(x, feats, fus_w, fus_b, cas, pre1);
  k_mask<<<2*((NB*NL)/256), 256, 0, stream>>>(pre1, c11_w, crw, crb, x, mask);

  // ---- phase 2 ----
  k_xe<<<(NB*NL)/256, 256, 0, stream>>>(mask, match_w, match_b, xe, xeh, xenh);
  k_yeh<<<(NB*NL)/256, 256, 0, stream>>>(mask, asm_w, asm_b, yeh);
  k_codes<<<(NB*NHASH*NL)/256, 256, 0, stream>>>(xe, rot, codes);
  k_zero<<<(NB*NKEY*NTILE + 255)/256, 256, 0, stream>>>(hist, NB*NKEY*NTILE);
  k_hist<<<NB*NTILE, 128, 0, stream>>>(codes, hist);
  k_scan<<<NB, 256, 0, stream>>>(hist, offs);
  k_scatter<<<NB*NTILE, 128, 0, stream>>>(codes, offs, idx, undo);
  k_attn<<<NB*NHASH*NCHUNKS, 512, 0, stream>>>(xeh, xenh, yeh, idx, retb, bsc);
  k_combine<<<(NB*NL)/256, 256, 0, stream>>>(retb, bsc, undo, mask, fea);
  k_collect<<<(NB*NL)/256, 256, 0, stream>>>(fea, col_w, col_b, x, out);
}

// Round 3
// 631.312 us; speedup vs baseline: 1.8664x; 1.7050x over previous
//
#include <hip/hip_runtime.h>
#include <math.h>

// ---------------- problem constants ----------------
static constexpr int NB = 2;
static constexpr int NC = 64;
static constexpr int NHp = 128, NWp = 128;
static constexpr int NL = NHp * NWp;     // 16384
static constexpr int NCR = 16;
static constexpr int NL2 = 64 * 64;      // 4096
static constexpr int NHASH = 4;
static constexpr int CHUNKSZ = 512;
static constexpr int NCHUNKS = 32;
static constexpr int TOT = NHASH * NL;   // 65536
static constexpr int NKEY = 128;
static constexpr int NTILE = 256;
static constexpr int TILESZ = TOT / NTILE; // 256

typedef _Float16 half4 __attribute__((ext_vector_type(4)));
typedef _Float16 half8 __attribute__((ext_vector_type(8)));
typedef float f32x4 __attribute__((ext_vector_type(4)));

// ---------------- workspace layout (float units) ----------------
static constexpr size_t OFF_MASK = 0;
static constexpr size_t OFF_FEA  = OFF_MASK + (size_t)NB*NC*NL;         // 2,097,152
static constexpr size_t OFF_XE   = OFF_FEA  + (size_t)NB*NC*NL;         // 4,194,304 fp32 [B*L][16]
static constexpr size_t OFF_XEH  = OFF_XE   + (size_t)NB*NL*NCR;        // 4,718,592 half
static constexpr size_t OFF_XENH = OFF_XEH  + (size_t)NB*NL*NCR/2;      // half
static constexpr size_t OFF_YEH  = OFF_XENH + (size_t)NB*NL*NCR/2;      // half [B*L][64]
static constexpr size_t OFF_RET  = OFF_YEH  + (size_t)NB*NL*NC/2;       // half [B*TOT][64]
static constexpr size_t OFF_BSC  = OFF_RET  + (size_t)NB*TOT*NC/2;      // 10,485,760
static constexpr size_t OFF_INT  = OFF_BSC  + (size_t)NB*TOT;
static constexpr size_t IOFF_CODES = 0;
static constexpr size_t IOFF_IDX   = IOFF_CODES + (size_t)NB*TOT;
static constexpr size_t IOFF_UNDO  = IOFF_IDX   + (size_t)NB*TOT;
static constexpr size_t IOFF_HIST  = IOFF_UNDO  + (size_t)NB*TOT;
static constexpr size_t IOFF_OFFS  = IOFF_HIST  + (size_t)NB*NKEY*NTILE/2;
static constexpr size_t IOFF_END   = IOFF_OFFS  + (size_t)NB*NKEY*NTILE/2;
static constexpr size_t OFF_CAY = OFF_INT + IOFF_END;
static constexpr size_t OFF_CAS = OFF_CAY + 128;
static constexpr size_t OFF_CRW = OFF_CAS + 128;
static constexpr size_t OFF_CRB = OFF_CRW + 4096;
// phase-1 overlays:
//  - half-res pipeline lives in the FEA region (dead until attnmul writes pre1)
static constexpr size_t OFF_PMX   = OFF_FEA;                            // 131072
static constexpr size_t OFF_PAV   = OFF_PMX  + (size_t)NB*NCR*NL2;      // 131072
static constexpr size_t OFF_PTMP  = OFF_PAV  + (size_t)NB*NCR*NL2;      // 786432 (6 combos)
static constexpr size_t OFF_DWT   = OFF_PTMP + (size_t)6*NB*NCR*NL2;    // 786432
static_assert(OFF_DWT + (size_t)6*NB*NCR*NL2 <= OFF_XE, "halfres overlay fits in fea region");
//  - xr + feats live in the phase-2 region (xe/xeh/ret), free during phase 1
static constexpr size_t OFF_XR    = OFF_XE;                             // 524,288
static constexpr size_t OFF_FEATS = OFF_XR + (size_t)NB*NCR*NL;         // 4,194,304
static_assert(OFF_FEATS + (size_t)NB*128*NL <= OFF_BSC, "feats overlay fits");
//  - pre1 overlays FEA (written after halfres pipeline is consumed)
static constexpr size_t OFF_PRE1  = OFF_FEA;

__device__ __forceinline__ float sigmoidf_(float v){ return 1.0f/(1.0f + expf(-v)); }

// ---------------- phase 1 ----------------

// xr = conv1x1(x, 64->16): acc[16] in regs, stream x in chunks of 16
__global__ void k_xr(const float* __restrict__ x, const float* __restrict__ w,
                     const float* __restrict__ b, float* __restrict__ xr){
  int gid = blockIdx.x*256 + threadIdx.x;
  if (gid >= NB*NL) return;
  int bb = gid >> 14, p = gid & (NL-1);
  const float* xi = x + (size_t)bb*NC*NL + p;
  float acc[16];
  #pragma unroll
  for (int oc=0; oc<16; ++oc) acc[oc] = b[oc];
  for (int ic0=0; ic0<64; ic0+=16){
    float r[16];
    #pragma unroll
    for (int j=0; j<16; ++j) r[j] = xi[(size_t)(ic0+j)*NL];
    #pragma unroll
    for (int oc=0; oc<16; ++oc){
      #pragma unroll
      for (int j=0; j<16; ++j) acc[oc] += r[j]*w[oc*64+ic0+j];
    }
  }
  float* xo = xr + (size_t)bb*NCR*NL + p;
  #pragma unroll
  for (int oc=0; oc<16; ++oc) xo[(size_t)oc*NL] = acc[oc];
}

// s0 = dw1x1(pw(xr,16->32)) -> feats channels [0,32)
__global__ void k_s0(const float* __restrict__ xr, const float* __restrict__ pw,
                     const float* __restrict__ dww, const float* __restrict__ dwb,
                     float* __restrict__ feats){
  int gid = blockIdx.x*256 + threadIdx.x;
  if (gid >= NB*NL) return;
  int bb = gid >> 14, p = gid & (NL-1);
  const float* xi = xr + (size_t)bb*NCR*NL + p;
  float r[16];
  #pragma unroll
  for (int ic=0; ic<16; ++ic) r[ic] = xi[(size_t)ic*NL];
  float* fo = feats + (size_t)bb*128*NL + p;
  #pragma unroll
  for (int oc=0; oc<32; ++oc){
    float s = 0.f;
    #pragma unroll
    for (int ic=0; ic<16; ++ic) s += r[ic]*pw[oc*16+ic];
    fo[(size_t)oc*NL] = s*dww[oc] + dwb[oc];
  }
}

__global__ void k_pool(const float* __restrict__ xr, float* __restrict__ pmax,
                       float* __restrict__ pavg){
  int gid = blockIdx.x*256 + threadIdx.x;
  if (gid >= NB*NCR*NL2) return;
  int p = gid & (NL2-1); int t = gid >> 12; int c = t & 15; int bb = t >> 4;
  int y = p >> 6, x2 = p & 63;
  const float* base = xr + (size_t)(bb*NCR + c)*NL + (size_t)(2*y)*NWp + 2*x2;
  float a = base[0], b_ = base[1], c_ = base[NWp], d = base[NWp+1];
  pmax[gid] = fmaxf(fmaxf(a,b_), fmaxf(c_,d));
  pavg[gid] = 0.25f*(a+b_+c_+d);
}

// fused pointwise 16->16 for all (br,mode): combo = br*2+mode
__global__ void k_pw16_all(const float* __restrict__ pmx, const float* __restrict__ pav,
                           const float* __restrict__ w0, const float* __restrict__ w1,
                           const float* __restrict__ w2, float* __restrict__ out){
  int gid = blockIdx.x*256 + threadIdx.x;
  if (gid >= 6*NB*NL2) return;
  int p = gid & (NL2-1); int t = gid >> 12; int bb = t & 1; int combo = t >> 1;
  int br = combo >> 1, mode = combo & 1;
  const float* w = (br==0) ? w0 : (br==1) ? w1 : w2;
  const float* in = ((mode==0) ? pmx : pav) + (size_t)bb*NCR*NL2 + p;
  float r[16];
  #pragma unroll
  for (int ic=0; ic<16; ++ic) r[ic] = in[(size_t)ic*NL2];
  float* oo = out + ((size_t)(combo*NB + bb)*NCR)*NL2 + p;
  #pragma unroll
  for (int oc=0; oc<16; ++oc){
    float s = 0.f;
    #pragma unroll
    for (int ic=0; ic<16; ++ic) s += r[ic]*w[oc*16+ic];
    oo[(size_t)oc*NL2] = s;
  }
}

// fused depthwise KxK for all combos
__global__ void k_dw_all(const float* __restrict__ in,
                         const float* __restrict__ w3, const float* __restrict__ b3,
                         const float* __restrict__ w5, const float* __restrict__ b5,
                         const float* __restrict__ w7, const float* __restrict__ b7,
                         float* __restrict__ out){
  int gid = blockIdx.x*256 + threadIdx.x;
  if (gid >= 6*NB*NCR*NL2) return;
  int p = gid & (NL2-1); int t = gid >> 12; int c = t & 15; int r2 = t >> 4;
  int bb = r2 & 1; int combo = r2 >> 1;
  int br = combo >> 1;
  int K = (br==0) ? 3 : (br==1) ? 5 : 7; int P = K >> 1;
  const float* w = (br==0) ? w3 : (br==1) ? w5 : w7;
  const float* bias = (br==0) ? b3 : (br==1) ? b5 : b7;
  int y = p >> 6, x = p & 63;
  const float* xi = in + ((size_t)(combo*NB + bb)*NCR + c)*NL2;
  float s = bias[c];
  for (int dy=0; dy<K; ++dy){
    int iy = y + dy - P;
    if ((unsigned)iy < 64u){
      for (int dx=0; dx<K; ++dx){
        int ix = x + dx - P;
        if ((unsigned)ix < 64u) s += xi[iy*64 + ix] * w[(c*K + dy)*K + dx];
      }
    }
  }
  out[gid] = s;
}

// fused bilinear upsample for all combos -> feats channels 32 + br*32 + mode*16 + c
__global__ void k_up_all(const float* __restrict__ in, float* __restrict__ feats){
  int gid = blockIdx.x*256 + threadIdx.x;
  if (gid >= 6*NB*NCR*NL) return;
  int p = gid & (NL-1); int t = gid >> 14; int c = t & 15; int r2 = t >> 4;
  int bb = r2 & 1; int combo = r2 >> 1;
  int y = p >> 7, x = p & 127;
  const float sc = 63.0f/127.0f;
  float fy = y*sc; int ly = (int)floorf(fy); int hy = min(ly+1, 63); fy -= (float)ly;
  float fx = x*sc; int lx = (int)floorf(fx); int hx = min(lx+1, 63); float gx = fx - (float)lx;
  const float* xi = in + ((size_t)(combo*NB + bb)*NCR + c)*NL2;
  float v0 = xi[ly*64+lx]*(1.f-fy) + xi[hy*64+lx]*fy;
  float v1 = xi[ly*64+hx]*(1.f-fy) + xi[hy*64+hx]*fy;
  int coff = 32 + combo*16 + c;   // br*32 + mode*16 + c
  feats[(size_t)bb*128*NL + (size_t)coff*NL + p] = v0*(1.f-gx) + v1*gx;
}

__global__ void k_camean(const float* __restrict__ x, float* __restrict__ cay){
  __shared__ float red[256];
  int bc = blockIdx.x; int tid = threadIdx.x;
  float s = 0.f;
  for (int i = tid; i < NL; i += 256) s += x[(size_t)bc*NL + i];
  red[tid] = s; __syncthreads();
  for (int st=128; st>0; st>>=1){ if (tid<st) red[tid]+=red[tid+st]; __syncthreads(); }
  if (tid==0) cay[bc] = red[0] / (float)NL;
}

__global__ void k_camlp(const float* __restrict__ cay,
                        const float* __restrict__ w1, const float* __restrict__ b1,
                        const float* __restrict__ w2, const float* __restrict__ b2,
                        float* __restrict__ cas){
  __shared__ float z[NB*4];
  int tid = threadIdx.x;
  if (tid < NB*4){
    int bb = tid >> 2, j = tid & 3;
    float s = b1[j];
    for (int ic=0; ic<NC; ++ic) s += cay[bb*NC+ic]*w1[j*NC+ic];
    z[tid] = fmaxf(s, 0.f);
  }
  __syncthreads();
  if (tid < NB*NC){
    int bb = tid >> 6, oc = tid & 63;
    float s = b2[oc];
    #pragma unroll
    for (int j=0; j<4; ++j) s += z[bb*4+j]*w2[oc*4+j];
    cas[tid] = sigmoidf_(s);
  }
}

__global__ void k_wprod(const float* __restrict__ c11w, const float* __restrict__ c11b,
                        const float* __restrict__ rw, const float* __restrict__ rb,
                        float* __restrict__ crw, float* __restrict__ crb){
  int gid = blockIdx.x*256 + threadIdx.x;
  if (gid >= 4096) return;
  int o = gid >> 6, i = gid & 63;
  float s = 0.f;
  for (int k=0; k<64; ++k) s += c11w[o*64+k]*rw[k*64+i];
  crw[gid] = s;
  if (i == 0){
    float t = c11b[o];
    for (int k=0; k<64; ++k) t += c11w[o*64+k]*rb[k];
    crb[o] = t;
  }
}

// pre1 = x*(sigmoid(fusion(feats)) + ca): acc[64], stream feats in chunks of 8
__global__ void k_attnmul(const float* __restrict__ x, const float* __restrict__ feats,
                          const float* __restrict__ fw, const float* __restrict__ fb,
                          const float* __restrict__ cas, float* __restrict__ pre1){
  int gid = blockIdx.x*256 + threadIdx.x;
  if (gid >= NB*NL) return;
  int bb = gid >> 14, p = gid & (NL-1);
  const float* fi = feats + (size_t)bb*128*NL + p;
  float acc[64];
  #pragma unroll
  for (int oc=0; oc<64; ++oc) acc[oc] = fb[oc];
  for (int k0=0; k0<128; k0+=8){
    float fr[8];
    #pragma unroll
    for (int j=0; j<8; ++j) fr[j] = fi[(size_t)(k0+j)*NL];
    #pragma unroll
    for (int oc=0; oc<64; ++oc){
      #pragma unroll
      for (int j=0; j<8; ++j) acc[oc] += fr[j]*fw[oc*128+k0+j];
    }
  }
  const float* xb = x + (size_t)bb*NC*NL + p;
  float* po = pre1 + (size_t)bb*NC*NL + p;
  #pragma unroll
  for (int oc=0; oc<64; ++oc){
    float xv = xb[(size_t)oc*NL];
    po[(size_t)oc*NL] = xv*(sigmoidf_(acc[oc]) + cas[bb*64+oc]);
  }
}

// mask = conv1x1(pre1) + crw@x + crb + x : acc[64], stream pre1 & x chunks of 8
__global__ void k_mask(const float* __restrict__ pre1, const float* __restrict__ c11w,
                       const float* __restrict__ crw, const float* __restrict__ crb,
                       const float* __restrict__ x, float* __restrict__ mask){
  int gid = blockIdx.x*256 + threadIdx.x;
  if (gid >= NB*NL) return;
  int bb = gid >> 14, p = gid & (NL-1);
  const float* pi = pre1 + (size_t)bb*NC*NL + p;
  const float* xi = x + (size_t)bb*NC*NL + p;
  float acc[64];
  #pragma unroll
  for (int oc=0; oc<64; ++oc) acc[oc] = crb[oc];
  for (int ic0=0; ic0<64; ic0+=8){
    float pr[8], xr8[8];
    #pragma unroll
    for (int j=0; j<8; ++j){ pr[j] = pi[(size_t)(ic0+j)*NL]; xr8[j] = xi[(size_t)(ic0+j)*NL]; }
    #pragma unroll
    for (int oc=0; oc<64; ++oc){
      #pragma unroll
      for (int j=0; j<8; ++j)
        acc[oc] += pr[j]*c11w[oc*64+ic0+j] + xr8[j]*crw[oc*64+ic0+j];
    }
  }
  float* mo = mask + (size_t)bb*NC*NL + p;
  #pragma unroll
  for (int oc=0; oc<64; ++oc) mo[(size_t)oc*NL] = acc[oc] + xi[(size_t)oc*NL];
}

// ---------------- phase 2 ----------------

// xe fp32 (for codes) + xe half (Q) + normalized xe half (K)
__global__ void k_xe(const float* __restrict__ mask, const float* __restrict__ w,
                     const float* __restrict__ b, float* __restrict__ xe,
                     _Float16* __restrict__ xeh, _Float16* __restrict__ xenh){
  int gid = blockIdx.x*256 + threadIdx.x;
  if (gid >= NB*NL) return;
  int bb = gid >> 14; int l = gid & (NL-1);
  const float* mi = mask + (size_t)bb*NC*NL + l;
  float acc[16];
  #pragma unroll
  for (int oc=0; oc<16; ++oc) acc[oc] = b[oc];
  for (int ic0=0; ic0<64; ic0+=16){
    float r[16];
    #pragma unroll
    for (int j=0; j<16; ++j) r[j] = mi[(size_t)(ic0+j)*NL];
    #pragma unroll
    for (int oc=0; oc<16; ++oc){
      #pragma unroll
      for (int j=0; j<16; ++j) acc[oc] += r[j]*w[oc*64+ic0+j];
    }
  }
  float n2 = 0.f;
  #pragma unroll
  for (int oc=0; oc<16; ++oc) n2 += acc[oc]*acc[oc];
  float inv = 1.0f / fmaxf(sqrtf(n2), 5e-5f);
  float* xo = xe + (size_t)gid*NCR;
  _Float16* ho = xeh + (size_t)gid*NCR;
  _Float16* no = xenh + (size_t)gid*NCR;
  #pragma unroll
  for (int g=0; g<4; ++g){
    f32x4 v; half4 hv, nv;
    #pragma unroll
    for (int j=0; j<4; ++j){ v[j] = acc[g*4+j]; hv[j] = (_Float16)acc[g*4+j]; nv[j] = (_Float16)(acc[g*4+j]*inv); }
    *(f32x4*)(xo + g*4) = v;
    *(half4*)(ho + g*4) = hv;
    *(half4*)(no + g*4) = nv;
  }
}

// ye in half: acc[64], stream mask chunks of 8, vector half8 stores
__global__ void k_yeh(const float* __restrict__ mask, const float* __restrict__ w,
                      const float* __restrict__ b, _Float16* __restrict__ yeh){
  int gid = blockIdx.x*256 + threadIdx.x;
  if (gid >= NB*NL) return;
  int bb = gid >> 14; int l = gid & (NL-1);
  const float* mi = mask + (size_t)bb*NC*NL + l;
  float acc[64];
  #pragma unroll
  for (int oc=0; oc<64; ++oc) acc[oc] = b[oc];
  for (int ic0=0; ic0<64; ic0+=8){
    float r[8];
    #pragma unroll
    for (int j=0; j<8; ++j) r[j] = mi[(size_t)(ic0+j)*NL];
    #pragma unroll
    for (int oc=0; oc<64; ++oc){
      #pragma unroll
      for (int j=0; j<8; ++j) acc[oc] += r[j]*w[oc*64+ic0+j];
    }
  }
  _Float16* yo = yeh + (size_t)gid*NC;
  #pragma unroll
  for (int g=0; g<8; ++g){
    half8 h;
    #pragma unroll
    for (int j=0; j<8; ++j) h[j] = (_Float16)acc[g*8+j];
    *(half8*)(yo + g*8) = h;
  }
}

__global__ void k_codes(const float* __restrict__ xe, const float* __restrict__ rot,
                        int* __restrict__ codes){
  int gid = blockIdx.x*256 + threadIdx.x;
  if (gid >= NB*NHASH*NL) return;
  int l = gid & (NL-1); int t = gid >> 14; int h = t & 3; int bb = t >> 2;
  const float* v = xe + (size_t)(bb*NL + l)*NCR;
  float q[16];
  #pragma unroll
  for (int f=0; f<16; ++f) q[f] = v[f];
  float rv[16];
  #pragma unroll
  for (int i=0; i<16; ++i){
    float s = 0.f;
    #pragma unroll
    for (int f=0; f<16; ++f) s += q[f]*rot[(f*NHASH + h)*16 + i];
    rv[i] = s;
  }
  float best = -1e30f; int bi = 0;
  #pragma unroll
  for (int i=0; i<16; ++i){ if (rv[i] > best){ best = rv[i]; bi = i; } }
  #pragma unroll
  for (int i=0; i<16; ++i){ float val = -rv[i]; if (val > best){ best = val; bi = 16+i; } }
  codes[gid] = bi + h*32;
}

__global__ void k_zero(int* __restrict__ p, int n){
  int i = blockIdx.x*256 + threadIdx.x;
  if (i < n) p[i] = 0;
}

__global__ void k_hist(const int* __restrict__ codes, int* __restrict__ hist){
  __shared__ int h[NKEY];
  int bt = blockIdx.x; int bb = bt >> 8; int tile = bt & 255;
  int tid = threadIdx.x;
  h[tid] = 0; __syncthreads();
  for (int i = tid; i < TILESZ; i += 128)
    atomicAdd(&h[codes[bb*TOT + tile*TILESZ + i]], 1);
  __syncthreads();
  hist[bb*NKEY*NTILE + tid*NTILE + tile] = h[tid];
}

__global__ void k_scan(const int* __restrict__ hist, int* __restrict__ offs){
  __shared__ int part[256];
  int bb = blockIdx.x; int t = threadIdx.x;
  const int* hi = hist + (size_t)bb*NKEY*NTILE;
  int* oo = offs + (size_t)bb*NKEY*NTILE;
  int s = 0;
  for (int i=0; i<128; ++i) s += hi[t*128 + i];
  part[t] = s; __syncthreads();
  if (t == 0){ int acc = 0; for (int i=0;i<256;++i){ int v=part[i]; part[i]=acc; acc+=v; } }
  __syncthreads();
  int run = part[t];
  for (int i=0; i<128; ++i){ int v = hi[t*128+i]; oo[t*128+i] = run; run += v; }
}

__global__ void k_scatter(const int* __restrict__ codes, const int* __restrict__ offs,
                          int* __restrict__ idx, int* __restrict__ undo){
  __shared__ int cnt[NKEY];
  int tid = threadIdx.x;
  cnt[tid] = 0; __syncthreads();
  if (tid == 0){
    int bt = blockIdx.x; int bb = bt >> 8; int tile = bt & 255;
    const int* cb = codes + bb*TOT;
    const int* ob = offs + (size_t)bb*NKEY*NTILE;
    int* ib = idx + bb*TOT;
    int* ub = undo + bb*TOT;
    #pragma unroll 4
    for (int i=0; i<TILESZ; ++i){
      int j = tile*TILESZ + i;
      int k = cb[j];
      int pos = ob[k*NTILE + tile] + cnt[k]++;
      ib[pos] = j;
      ub[j] = pos;
    }
  }
}

// MFMA flash attention (unchanged from round 1)
__global__ __launch_bounds__(512) void k_attn(
    const _Float16* __restrict__ xeh, const _Float16* __restrict__ xenh,
    const _Float16* __restrict__ yeh, const int* __restrict__ idx,
    _Float16* __restrict__ retb, float* __restrict__ bsc){
  __shared__ _Float16 kt[64*24];
  __shared__ _Float16 vt[64*72];
  int blk = blockIdx.x;
  int kk = blk & 31; int h = (blk >> 5) & 3; int bb = blk >> 7;
  int tid = threadIdx.x;
  int w = tid >> 6, lane = tid & 63, col = lane & 15, grp = lane >> 4;
  const int* idxb = idx + bb*TOT;
  int qbase = h*NL + kk*CHUNKSZ + w*64;

  half4 qfr[4]; int posq[4];
  #pragma unroll
  for (int qf=0; qf<4; ++qf){
    posq[qf] = qbase + qf*16 + col;
    int lq = idxb[posq[qf]] & (NL-1);
    qfr[qf] = *(const half4*)(xeh + ((size_t)bb*NL + lq)*16 + grp*4);
  }

  f32x4 O[4][4];
  #pragma unroll
  for (int a=0; a<4; ++a)
    #pragma unroll
    for (int b=0; b<4; ++b) O[a][b] = (f32x4){0.f,0.f,0.f,0.f};
  float m_[4] = {-1e30f,-1e30f,-1e30f,-1e30f};
  float ssum[4] = {0.f,0.f,0.f,0.f};

  for (int t=0; t<24; ++t){
    __syncthreads();
    {
      int kx = tid & 63, c0 = (tid >> 6) * 8;
      int jj = t*64 + kx; int sec = jj >> 9; int j0 = jj & 511;
      int cc = kk + ((sec==1) ? -1 : (sec==2) ? 1 : 0);
      cc = (cc + NCHUNKS) & (NCHUNKS-1);
      int lv = idxb[h*NL + cc*CHUNKSZ + j0] & (NL-1);
      half8 vv = *(const half8*)(yeh + ((size_t)bb*NL + lv)*64 + c0);
      #pragma unroll
      for (int j=0; j<8; ++j) vt[(c0+j)*72 + kx] = vv[j];
    }
    if (tid < 128){
      int r = tid >> 1, hf = tid & 1;
      int jj = t*64 + r; int sec = jj >> 9; int j0 = jj & 511;
      int cc = kk + ((sec==1) ? -1 : (sec==2) ? 1 : 0);
      cc = (cc + NCHUNKS) & (NCHUNKS-1);
      int lk = idxb[h*NL + cc*CHUNKSZ + j0] & (NL-1);
      *(half8*)(kt + r*24 + hf*8) =
          *(const half8*)(xenh + ((size_t)bb*NL + lk)*16 + hf*8);
    }
    __syncthreads();

    f32x4 S[4][4];
    #pragma unroll
    for (int kb=0; kb<4; ++kb){
      half4 ka = *(const half4*)(kt + (kb*16 + col)*24 + grp*4);
      #pragma unroll
      for (int qf=0; qf<4; ++qf)
        S[kb][qf] = __builtin_amdgcn_mfma_f32_16x16x16f16(
            ka, qfr[qf], (f32x4){0.f,0.f,0.f,0.f}, 0, 0, 0);
    }

    half4 pf[4][4];
    #pragma unroll
    for (int qf=0; qf<4; ++qf){
      float mt = -1e30f;
      #pragma unroll
      for (int kb=0; kb<4; ++kb)
        #pragma unroll
        for (int i=0; i<4; ++i) mt = fmaxf(mt, S[kb][qf][i]);
      mt = fmaxf(mt, __shfl_xor(mt, 16, 64));
      mt = fmaxf(mt, __shfl_xor(mt, 32, 64));
      float mn = fmaxf(m_[qf], mt);
      float sc = __expf(m_[qf] - mn);
      float ps = 0.f;
      #pragma unroll
      for (int kb=0; kb<4; ++kb){
        #pragma unroll
        for (int i=0; i<4; ++i){
          float p = __expf(S[kb][qf][i] - mn);
          ps += p;
          pf[qf][kb][i] = (_Float16)p;
        }
      }
      ps += __shfl_xor(ps, 16, 64);
      ps += __shfl_xor(ps, 32, 64);
      ssum[qf] = ssum[qf]*sc + ps;
      m_[qf] = mn;
      #pragma unroll
      for (int cf=0; cf<4; ++cf)
        #pragma unroll
        for (int i=0; i<4; ++i) O[cf][qf][i] *= sc;
    }

    #pragma unroll
    for (int cf=0; cf<4; ++cf){
      #pragma unroll
      for (int kb=0; kb<4; ++kb){
        half4 va = *(const half4*)(vt + (cf*16 + col)*72 + kb*16 + grp*4);
        #pragma unroll
        for (int qf=0; qf<4; ++qf)
          O[cf][qf] = __builtin_amdgcn_mfma_f32_16x16x16f16(
              va, pf[qf][kb], O[cf][qf], 0, 0, 0);
      }
    }
  }

  #pragma unroll
  for (int qf=0; qf<4; ++qf){
    float inv = 1.0f/ssum[qf];
    size_t rb = ((size_t)bb*TOT + posq[qf])*64;
    #pragma unroll
    for (int cf=0; cf<4; ++cf){
      half4 o;
      #pragma unroll
      for (int i=0; i<4; ++i) o[i] = (_Float16)(O[cf][qf][i]*inv);
      *(half4*)(retb + rb + cf*16 + grp*4) = o;
    }
    if (grp == 0) bsc[(size_t)bb*TOT + posq[qf]] = m_[qf] + logf(ssum[qf]);
  }
}

__global__ void k_combine(const _Float16* __restrict__ retb, const float* __restrict__ bsc,
                          const int* __restrict__ undo, const float* __restrict__ mask,
                          float* __restrict__ fea){
  int gid = blockIdx.x*256 + threadIdx.x;
  if (gid >= NB*NL) return;
  int bb = gid >> 14; int l = gid & (NL-1);
  const int* ub = undo + bb*TOT;
  int pos[4]; float sc[4];
  #pragma unroll
  for (int h=0; h<4; ++h){ pos[h] = ub[h*NL + l]; sc[h] = bsc[bb*TOT + pos[h]]; }
  float mx = fmaxf(fmaxf(sc[0],sc[1]), fmaxf(sc[2],sc[3]));
  float e[4]; float tot = 0.f;
  #pragma unroll
  for (int h=0; h<4; ++h){ e[h] = __expf(sc[h]-mx); tot += e[h]; }
  float inv = 0.1f/tot;
  const float* mb_ = mask + (size_t)bb*NC*NL + l;
  float* fo = fea + (size_t)bb*NC*NL + l;
  const _Float16* r0 = retb + ((size_t)bb*TOT + pos[0])*NC;
  const _Float16* r1 = retb + ((size_t)bb*TOT + pos[1])*NC;
  const _Float16* r2 = retb + ((size_t)bb*TOT + pos[2])*NC;
  const _Float16* r3 = retb + ((size_t)bb*TOT + pos[3])*NC;
  #pragma unroll
  for (int g=0; g<8; ++g){
    half8 v0 = *(const half8*)(r0 + g*8);
    half8 v1 = *(const half8*)(r1 + g*8);
    half8 v2 = *(const half8*)(r2 + g*8);
    half8 v3 = *(const half8*)(r3 + g*8);
    #pragma unroll
    for (int j=0; j<8; ++j){
      int c = g*8 + j;
      float v = (float)v0[j]*e[0] + (float)v1[j]*e[1] + (float)v2[j]*e[2] + (float)v3[j]*e[3];
      fo[(size_t)c*NL] = v*inv + mb_[(size_t)c*NL];
    }
  }
}

__global__ void k_collect(const float* __restrict__ fea, const float* __restrict__ w,
                          const float* __restrict__ b, const float* __restrict__ x,
                          float* __restrict__ out){
  int gid = blockIdx.x*256 + threadIdx.x;
  if (gid >= NB*NL) return;
  int bb = gid >> 14, p = gid & (NL-1);
  const float* fi = fea + (size_t)bb*NC*NL + p;
  const float* xi = x + (size_t)bb*NC*NL + p;
  float acc[64];
  #pragma unroll
  for (int oc=0; oc<64; ++oc) acc[oc] = b[oc];
  for (int ic0=0; ic0<64; ic0+=8){
    float r[8];
    #pragma unroll
    for (int j=0; j<8; ++j) r[j] = fi[(size_t)(ic0+j)*NL];
    #pragma unroll
    for (int oc=0; oc<64; ++oc){
      #pragma unroll
      for (int j=0; j<8; ++j) acc[oc] += r[j]*w[oc*64+ic0+j];
    }
  }
  float* oo = out + (size_t)bb*NC*NL + p;
  #pragma unroll
  for (int oc=0; oc<64; ++oc) oo[(size_t)oc*NL] = acc[oc] + xi[(size_t)oc*NL];
}

// ---------------- launcher ----------------
extern "C" void kernel_launch(void* const* d_in, const int* in_sizes, int n_in,
                              void* d_out, int out_size, void* d_ws, size_t ws_size,
                              hipStream_t stream) {
  const float* x        = (const float*)d_in[0];
  const float* spa_dw   = (const float*)d_in[1];
  const float* spa_db   = (const float*)d_in[2];
  const float* s0_pw    = (const float*)d_in[3];
  const float* s0_dww   = (const float*)d_in[4];
  const float* s0_dwb   = (const float*)d_in[5];
  const float* fus_w    = (const float*)d_in[15];
  const float* fus_b    = (const float*)d_in[16];
  const float* res_w    = (const float*)d_in[17];
  const float* res_b    = (const float*)d_in[18];
  const float* ca_w1    = (const float*)d_in[19];
  const float* ca_b1    = (const float*)d_in[20];
  const float* ca_w2    = (const float*)d_in[21];
  const float* ca_b2    = (const float*)d_in[22];
  const float* c11_w    = (const float*)d_in[23];
  const float* c11_b    = (const float*)d_in[24];
  const float* match_w  = (const float*)d_in[25];
  const float* match_b  = (const float*)d_in[26];
  const float* asm_w    = (const float*)d_in[27];
  const float* asm_b    = (const float*)d_in[28];
  const float* rot      = (const float*)d_in[29];
  const float* col_w    = (const float*)d_in[30];
  const float* col_b    = (const float*)d_in[31];
  float* out = (float*)d_out;

  float* ws    = (float*)d_ws;
  float* mask  = ws + OFF_MASK;
  float* fea   = ws + OFF_FEA;
  float* xe    = ws + OFF_XE;
  _Float16* xeh  = (_Float16*)(ws + OFF_XEH);
  _Float16* xenh = (_Float16*)(ws + OFF_XENH);
  _Float16* yeh  = (_Float16*)(ws + OFF_YEH);
  _Float16* retb = (_Float16*)(ws + OFF_RET);
  float* bsc   = ws + OFF_BSC;
  int*   ib    = (int*)(ws + OFF_INT);
  int* codes   = ib + IOFF_CODES;
  int* idx     = ib + IOFF_IDX;
  int* undo    = ib + IOFF_UNDO;
  int* hist    = ib + IOFF_HIST;
  int* offs    = ib + IOFF_OFFS;
  float* cay   = ws + OFF_CAY;
  float* cas   = ws + OFF_CAS;
  float* crw   = ws + OFF_CRW;
  float* crb   = ws + OFF_CRB;
  float* xr    = ws + OFF_XR;
  float* feats = ws + OFF_FEATS;
  float* pmx   = ws + OFF_PMX;
  float* pav   = ws + OFF_PAV;
  float* ptmp  = ws + OFF_PTMP;
  float* dwt   = ws + OFF_DWT;
  float* pre1  = ws + OFF_PRE1;

  // ---- phase 1 ----
  k_xr<<<(NB*NL)/256, 256, 0, stream>>>(x, spa_dw, spa_db, xr);
  k_wprod<<<16, 256, 0, stream>>>(c11_w, c11_b, res_w, res_b, crw, crb);
  k_s0<<<(NB*NL)/256, 256, 0, stream>>>(xr, s0_pw, s0_dww, s0_dwb, feats);
  k_pool<<<(NB*NCR*NL2)/256, 256, 0, stream>>>(xr, pmx, pav);
  k_pw16_all<<<(6*NB*NL2)/256, 256, 0, stream>>>(pmx, pav,
      (const float*)d_in[6], (const float*)d_in[9], (const float*)d_in[12], ptmp);
  k_dw_all<<<(6*NB*NCR*NL2)/256, 256, 0, stream>>>(ptmp,
      (const float*)d_in[7], (const float*)d_in[8],
      (const float*)d_in[10], (const float*)d_in[11],
      (const float*)d_in[13], (const float*)d_in[14], dwt);
  k_up_all<<<(6*NB*NCR*NL)/256, 256, 0, stream>>>(dwt, feats);
  k_camean<<<NB*NC, 256, 0, stream>>>(x, cay);
  k_camlp<<<1, 128, 0, stream>>>(cay, ca_w1, ca_b1, ca_w2, ca_b2, cas);
  k_attnmul<<<(NB*NL)/256, 256, 0, stream>>>(x, feats, fus_w, fus_b, cas, pre1);
  k_mask<<<(NB*NL)/256, 256, 0, stream>>>(pre1, c11_w, crw, crb, x, mask);

  // ---- phase 2 ----
  k_xe<<<(NB*NL)/256, 256, 0, stream>>>(mask, match_w, match_b, xe, xeh, xenh);
  k_yeh<<<(NB*NL)/256, 256, 0, stream>>>(mask, asm_w, asm_b, yeh);
  k_codes<<<(NB*NHASH*NL)/256, 256, 0, stream>>>(xe, rot, codes);
  k_zero<<<(NB*NKEY*NTILE + 255)/256, 256, 0, stream>>>(hist, NB*NKEY*NTILE);
  k_hist<<<NB*NTILE, 128, 0, stream>>>(codes, hist);
  k_scan<<<NB, 256, 0, stream>>>(hist, offs);
  k_scatter<<<NB*NTILE, 128, 0, stream>>>(codes, offs, idx, undo);
  k_attn<<<NB*NHASH*NCHUNKS, 512, 0, stream>>>(xeh, xenh, yeh, idx, retb, bsc);
  k_combine<<<(NB*NL)/256, 256, 0, stream>>>(retb, bsc, undo, mask, fea);
  k_collect<<<(NB*NL)/256, 256, 0, stream>>>(fea, col_w, col_b, x, out);
}

// Round 4
// 348.593 us; speedup vs baseline: 3.3801x; 1.8110x over previous
//
#include <hip/hip_runtime.h>
#include <math.h>

// ---------------- problem constants ----------------
static constexpr int NB = 2;
static constexpr int NC = 64;
static constexpr int NHp = 128, NWp = 128;
static constexpr int NL = NHp * NWp;     // 16384
static constexpr int NCR = 16;
static constexpr int NL2 = 64 * 64;      // 4096
static constexpr int NHASH = 4;
static constexpr int CHUNKSZ = 512;
static constexpr int NCHUNKS = 32;
static constexpr int TOT = NHASH * NL;   // 65536
static constexpr int NKEY = 128;
static constexpr int NTILE = 256;
static constexpr int TILESZ = TOT / NTILE; // 256

typedef _Float16 half4 __attribute__((ext_vector_type(4)));
typedef _Float16 half8 __attribute__((ext_vector_type(8)));
typedef float f32x4 __attribute__((ext_vector_type(4)));

// ---------------- workspace layout (float units) ----------------
static constexpr size_t OFF_MASK = 0;
static constexpr size_t OFF_FEA  = OFF_MASK + (size_t)NB*NC*NL;
static constexpr size_t OFF_XE   = OFF_FEA  + (size_t)NB*NC*NL;
static constexpr size_t OFF_XEH  = OFF_XE   + (size_t)NB*NL*NCR;
static constexpr size_t OFF_XENH = OFF_XEH  + (size_t)NB*NL*NCR/2;
static constexpr size_t OFF_YEH  = OFF_XENH + (size_t)NB*NL*NCR/2;
static constexpr size_t OFF_RET  = OFF_YEH  + (size_t)NB*NL*NC/2;
static constexpr size_t OFF_BSC  = OFF_RET  + (size_t)NB*TOT*NC/2;
static constexpr size_t OFF_INT  = OFF_BSC  + (size_t)NB*TOT;
static constexpr size_t IOFF_CODES = 0;
static constexpr size_t IOFF_IDX   = IOFF_CODES + (size_t)NB*TOT;
static constexpr size_t IOFF_UNDO  = IOFF_IDX   + (size_t)NB*TOT;
static constexpr size_t IOFF_HIST  = IOFF_UNDO  + (size_t)NB*TOT;
static constexpr size_t IOFF_OFFS  = IOFF_HIST  + (size_t)NB*NKEY*NTILE/2;
static constexpr size_t IOFF_END   = IOFF_OFFS  + (size_t)NB*NKEY*NTILE/2;
static constexpr size_t OFF_CAY = OFF_INT + IOFF_END;
static constexpr size_t OFF_CAS = OFF_CAY + 128;
static constexpr size_t OFF_CRW = OFF_CAS + 128;
static constexpr size_t OFF_CRB = OFF_CRW + 4096;
// phase-1 overlays
static constexpr size_t OFF_PMX   = OFF_FEA;
static constexpr size_t OFF_PAV   = OFF_PMX  + (size_t)NB*NCR*NL2;
static constexpr size_t OFF_PTMP  = OFF_PAV  + (size_t)NB*NCR*NL2;
static constexpr size_t OFF_DWT   = OFF_PTMP + (size_t)6*NB*NCR*NL2;
static_assert(OFF_DWT + (size_t)6*NB*NCR*NL2 <= OFF_XE, "halfres overlay fits");
static constexpr size_t OFF_XR    = OFF_XE;
static constexpr size_t OFF_FEATS = OFF_XR + (size_t)NB*NCR*NL;
static_assert(OFF_FEATS + (size_t)NB*128*NL <= OFF_BSC, "feats overlay fits");
static constexpr size_t OFF_PRE1  = OFF_FEA;

__device__ __forceinline__ float sigmoidf_(float v){ return 1.0f/(1.0f + expf(-v)); }

// ---------------- phase 1 ----------------

// xr = conv1x1(x,64->16): lane pairs split ic halves, shfl-combine
__global__ __launch_bounds__(256,4) void k_xr(const float* __restrict__ x,
                     const float* __restrict__ w,
                     const float* __restrict__ b, float* __restrict__ xr){
  int gid = blockIdx.x*256 + threadIdx.x;      // 2 threads per pixel
  int pix = gid >> 1, hf = gid & 1;
  int bb = pix >> 14, p = pix & (NL-1);
  const float* xi = x + (size_t)bb*NC*NL + (size_t)hf*32*NL + p;
  float acc[16];
  #pragma unroll
  for (int oc=0; oc<16; ++oc) acc[oc] = hf ? 0.f : b[oc];
  for (int ic0=0; ic0<32; ic0+=16){
    float r[16];
    #pragma unroll
    for (int j=0; j<16; ++j) r[j] = xi[(size_t)(ic0+j)*NL];
    #pragma unroll
    for (int oc=0; oc<16; ++oc){
      #pragma unroll
      for (int j=0; j<16; ++j) acc[oc] += r[j]*w[oc*64 + hf*32 + ic0 + j];
    }
  }
  #pragma unroll
  for (int oc=0; oc<16; ++oc) acc[oc] += __shfl_xor(acc[oc], 1, 64);
  if (!hf){
    float* xo = xr + (size_t)bb*NCR*NL + p;
    #pragma unroll
    for (int oc=0; oc<16; ++oc) xo[(size_t)oc*NL] = acc[oc];
  }
}

// s0: oc split 2-way via blockIdx.y
__global__ __launch_bounds__(256,4) void k_s0(const float* __restrict__ xr,
                     const float* __restrict__ pw,
                     const float* __restrict__ dww, const float* __restrict__ dwb,
                     float* __restrict__ feats){
  int gid = blockIdx.x*256 + threadIdx.x;
  int oc0 = blockIdx.y*16;
  int bb = gid >> 14, p = gid & (NL-1);
  const float* xi = xr + (size_t)bb*NCR*NL + p;
  float r[16];
  #pragma unroll
  for (int ic=0; ic<16; ++ic) r[ic] = xi[(size_t)ic*NL];
  float* fo = feats + (size_t)bb*128*NL + p;
  #pragma unroll
  for (int j=0; j<16; ++j){
    int oc = oc0 + j;
    float s = 0.f;
    #pragma unroll
    for (int ic=0; ic<16; ++ic) s += r[ic]*pw[oc*16+ic];
    fo[(size_t)oc*NL] = s*dww[oc] + dwb[oc];
  }
}

__global__ void k_pool(const float* __restrict__ xr, float* __restrict__ pmax,
                       float* __restrict__ pavg){
  int gid = blockIdx.x*256 + threadIdx.x;
  if (gid >= NB*NCR*NL2) return;
  int p = gid & (NL2-1); int t = gid >> 12; int c = t & 15; int bb = t >> 4;
  int y = p >> 6, x2 = p & 63;
  const float* base = xr + (size_t)(bb*NCR + c)*NL + (size_t)(2*y)*NWp + 2*x2;
  float a = base[0], b_ = base[1], c_ = base[NWp], d = base[NWp+1];
  pmax[gid] = fmaxf(fmaxf(a,b_), fmaxf(c_,d));
  pavg[gid] = 0.25f*(a+b_+c_+d);
}

__global__ void k_pw16_all(const float* __restrict__ pmx, const float* __restrict__ pav,
                           const float* __restrict__ w0, const float* __restrict__ w1,
                           const float* __restrict__ w2, float* __restrict__ out){
  int gid = blockIdx.x*256 + threadIdx.x;
  if (gid >= 6*NB*NL2) return;
  int p = gid & (NL2-1); int t = gid >> 12; int bb = t & 1; int combo = t >> 1;
  int br = combo >> 1, mode = combo & 1;
  const float* w = (br==0) ? w0 : (br==1) ? w1 : w2;
  const float* in = ((mode==0) ? pmx : pav) + (size_t)bb*NCR*NL2 + p;
  float r[16];
  #pragma unroll
  for (int ic=0; ic<16; ++ic) r[ic] = in[(size_t)ic*NL2];
  float* oo = out + ((size_t)(combo*NB + bb)*NCR)*NL2 + p;
  #pragma unroll
  for (int oc=0; oc<16; ++oc){
    float s = 0.f;
    #pragma unroll
    for (int ic=0; ic<16; ++ic) s += r[ic]*w[oc*16+ic];
    oo[(size_t)oc*NL2] = s;
  }
}

__global__ void k_dw_all(const float* __restrict__ in,
                         const float* __restrict__ w3, const float* __restrict__ b3,
                         const float* __restrict__ w5, const float* __restrict__ b5,
                         const float* __restrict__ w7, const float* __restrict__ b7,
                         float* __restrict__ out){
  int gid = blockIdx.x*256 + threadIdx.x;
  if (gid >= 6*NB*NCR*NL2) return;
  int p = gid & (NL2-1); int t = gid >> 12; int c = t & 15; int r2 = t >> 4;
  int bb = r2 & 1; int combo = r2 >> 1;
  int br = combo >> 1;
  int K = (br==0) ? 3 : (br==1) ? 5 : 7; int P = K >> 1;
  const float* w = (br==0) ? w3 : (br==1) ? w5 : w7;
  const float* bias = (br==0) ? b3 : (br==1) ? b5 : b7;
  int y = p >> 6, x = p & 63;
  const float* xi = in + ((size_t)(combo*NB + bb)*NCR + c)*NL2;
  float s = bias[c];
  for (int dy=0; dy<K; ++dy){
    int iy = y + dy - P;
    if ((unsigned)iy < 64u){
      for (int dx=0; dx<K; ++dx){
        int ix = x + dx - P;
        if ((unsigned)ix < 64u) s += xi[iy*64 + ix] * w[(c*K + dy)*K + dx];
      }
    }
  }
  out[gid] = s;
}

__global__ void k_up_all(const float* __restrict__ in, float* __restrict__ feats){
  int gid = blockIdx.x*256 + threadIdx.x;
  if (gid >= 6*NB*NCR*NL) return;
  int p = gid & (NL-1); int t = gid >> 14; int c = t & 15; int r2 = t >> 4;
  int bb = r2 & 1; int combo = r2 >> 1;
  int y = p >> 7, x = p & 127;
  const float sc = 63.0f/127.0f;
  float fy = y*sc; int ly = (int)floorf(fy); int hy = min(ly+1, 63); fy -= (float)ly;
  float fx = x*sc; int lx = (int)floorf(fx); int hx = min(lx+1, 63); float gx = fx - (float)lx;
  const float* xi = in + ((size_t)(combo*NB + bb)*NCR + c)*NL2;
  float v0 = xi[ly*64+lx]*(1.f-fy) + xi[hy*64+lx]*fy;
  float v1 = xi[ly*64+hx]*(1.f-fy) + xi[hy*64+hx]*fy;
  int coff = 32 + combo*16 + c;
  feats[(size_t)bb*128*NL + (size_t)coff*NL + p] = v0*(1.f-gx) + v1*gx;
}

__global__ void k_camean(const float* __restrict__ x, float* __restrict__ cay){
  __shared__ float red[256];
  int bc = blockIdx.x; int tid = threadIdx.x;
  float s = 0.f;
  for (int i = tid; i < NL; i += 256) s += x[(size_t)bc*NL + i];
  red[tid] = s; __syncthreads();
  for (int st=128; st>0; st>>=1){ if (tid<st) red[tid]+=red[tid+st]; __syncthreads(); }
  if (tid==0) cay[bc] = red[0] / (float)NL;
}

__global__ void k_camlp(const float* __restrict__ cay,
                        const float* __restrict__ w1, const float* __restrict__ b1,
                        const float* __restrict__ w2, const float* __restrict__ b2,
                        float* __restrict__ cas){
  __shared__ float z[NB*4];
  int tid = threadIdx.x;
  if (tid < NB*4){
    int bb = tid >> 2, j = tid & 3;
    float s = b1[j];
    for (int ic=0; ic<NC; ++ic) s += cay[bb*NC+ic]*w1[j*NC+ic];
    z[tid] = fmaxf(s, 0.f);
  }
  __syncthreads();
  if (tid < NB*NC){
    int bb = tid >> 6, oc = tid & 63;
    float s = b2[oc];
    #pragma unroll
    for (int j=0; j<4; ++j) s += z[bb*4+j]*w2[oc*4+j];
    cas[tid] = sigmoidf_(s);
  }
}

__global__ void k_wprod(const float* __restrict__ c11w, const float* __restrict__ c11b,
                        const float* __restrict__ rw, const float* __restrict__ rb,
                        float* __restrict__ crw, float* __restrict__ crb){
  int gid = blockIdx.x*256 + threadIdx.x;
  if (gid >= 4096) return;
  int o = gid >> 6, i = gid & 63;
  float s = 0.f;
  for (int k=0; k<64; ++k) s += c11w[o*64+k]*rw[k*64+i];
  crw[gid] = s;
  if (i == 0){
    float t = c11b[o];
    for (int k=0; k<64; ++k) t += c11w[o*64+k]*rb[k];
    crb[o] = t;
  }
}

// pre1 = x*(sigmoid(fusion(feats)) + ca): oc split 4-way via blockIdx.y
__global__ __launch_bounds__(256,4) void k_attnmul(const float* __restrict__ x,
                          const float* __restrict__ feats,
                          const float* __restrict__ fw, const float* __restrict__ fb,
                          const float* __restrict__ cas, float* __restrict__ pre1){
  int gid = blockIdx.x*256 + threadIdx.x;
  int oc0 = blockIdx.y*16;
  int bb = gid >> 14, p = gid & (NL-1);
  const float* fi = feats + (size_t)bb*128*NL + p;
  float acc[16];
  #pragma unroll
  for (int j=0; j<16; ++j) acc[j] = fb[oc0+j];
  for (int k0=0; k0<128; k0+=8){
    float fr[8];
    #pragma unroll
    for (int j=0; j<8; ++j) fr[j] = fi[(size_t)(k0+j)*NL];
    #pragma unroll
    for (int j=0; j<16; ++j){
      #pragma unroll
      for (int t=0; t<8; ++t) acc[j] += fr[t]*fw[(oc0+j)*128+k0+t];
    }
  }
  const float* xb = x + (size_t)bb*NC*NL + p;
  float* po = pre1 + (size_t)bb*NC*NL + p;
  #pragma unroll
  for (int j=0; j<16; ++j){
    int oc = oc0 + j;
    float xv = xb[(size_t)oc*NL];
    po[(size_t)oc*NL] = xv*(sigmoidf_(acc[j]) + cas[bb*64+oc]);
  }
}

// mask = conv1x1(pre1) + crw@x + crb + x : oc split 4-way
__global__ __launch_bounds__(256,4) void k_mask(const float* __restrict__ pre1,
                       const float* __restrict__ c11w,
                       const float* __restrict__ crw, const float* __restrict__ crb,
                       const float* __restrict__ x, float* __restrict__ mask){
  int gid = blockIdx.x*256 + threadIdx.x;
  int oc0 = blockIdx.y*16;
  int bb = gid >> 14, p = gid & (NL-1);
  const float* pi = pre1 + (size_t)bb*NC*NL + p;
  const float* xi = x + (size_t)bb*NC*NL + p;
  float acc[16];
  #pragma unroll
  for (int j=0; j<16; ++j) acc[j] = crb[oc0+j];
  for (int ic0=0; ic0<64; ic0+=8){
    float pr[8], xr8[8];
    #pragma unroll
    for (int j=0; j<8; ++j){ pr[j] = pi[(size_t)(ic0+j)*NL]; xr8[j] = xi[(size_t)(ic0+j)*NL]; }
    #pragma unroll
    for (int j=0; j<16; ++j){
      #pragma unroll
      for (int t=0; t<8; ++t)
        acc[j] += pr[t]*c11w[(oc0+j)*64+ic0+t] + xr8[t]*crw[(oc0+j)*64+ic0+t];
    }
  }
  float* mo = mask + (size_t)bb*NC*NL + p;
  #pragma unroll
  for (int j=0; j<16; ++j){
    int oc = oc0 + j;
    mo[(size_t)oc*NL] = acc[j] + xi[(size_t)oc*NL];
  }
}

// ---------------- phase 2 ----------------

// xe: lane pairs split ic halves, shfl-combine, even lane normalizes+writes
__global__ __launch_bounds__(256,4) void k_xe(const float* __restrict__ mask,
                     const float* __restrict__ w,
                     const float* __restrict__ b, float* __restrict__ xe,
                     _Float16* __restrict__ xeh, _Float16* __restrict__ xenh){
  int gid = blockIdx.x*256 + threadIdx.x;
  int pix = gid >> 1, hf = gid & 1;
  int bb = pix >> 14, l = pix & (NL-1);
  const float* mi = mask + (size_t)bb*NC*NL + (size_t)hf*32*NL + l;
  float acc[16];
  #pragma unroll
  for (int oc=0; oc<16; ++oc) acc[oc] = hf ? 0.f : b[oc];
  for (int ic0=0; ic0<32; ic0+=16){
    float r[16];
    #pragma unroll
    for (int j=0; j<16; ++j) r[j] = mi[(size_t)(ic0+j)*NL];
    #pragma unroll
    for (int oc=0; oc<16; ++oc){
      #pragma unroll
      for (int j=0; j<16; ++j) acc[oc] += r[j]*w[oc*64 + hf*32 + ic0 + j];
    }
  }
  #pragma unroll
  for (int oc=0; oc<16; ++oc) acc[oc] += __shfl_xor(acc[oc], 1, 64);
  if (!hf){
    float n2 = 0.f;
    #pragma unroll
    for (int oc=0; oc<16; ++oc) n2 += acc[oc]*acc[oc];
    float inv = 1.0f / fmaxf(sqrtf(n2), 5e-5f);
    float* xo = xe + (size_t)pix*NCR;
    _Float16* ho = xeh + (size_t)pix*NCR;
    _Float16* no = xenh + (size_t)pix*NCR;
    #pragma unroll
    for (int g=0; g<4; ++g){
      f32x4 v; half4 hv, nv;
      #pragma unroll
      for (int j=0; j<4; ++j){ v[j] = acc[g*4+j]; hv[j] = (_Float16)acc[g*4+j]; nv[j] = (_Float16)(acc[g*4+j]*inv); }
      *(f32x4*)(xo + g*4) = v;
      *(half4*)(ho + g*4) = hv;
      *(half4*)(no + g*4) = nv;
    }
  }
}

// ye: oc split 4-way
__global__ __launch_bounds__(256,4) void k_yeh(const float* __restrict__ mask,
                      const float* __restrict__ w,
                      const float* __restrict__ b, _Float16* __restrict__ yeh){
  int gid = blockIdx.x*256 + threadIdx.x;
  int oc0 = blockIdx.y*16;
  int bb = gid >> 14, l = gid & (NL-1);
  const float* mi = mask + (size_t)bb*NC*NL + l;
  float acc[16];
  #pragma unroll
  for (int j=0; j<16; ++j) acc[j] = b[oc0+j];
  for (int ic0=0; ic0<64; ic0+=8){
    float r[8];
    #pragma unroll
    for (int j=0; j<8; ++j) r[j] = mi[(size_t)(ic0+j)*NL];
    #pragma unroll
    for (int j=0; j<16; ++j){
      #pragma unroll
      for (int t=0; t<8; ++t) acc[j] += r[t]*w[(oc0+j)*64+ic0+t];
    }
  }
  _Float16* yo = yeh + (size_t)(bb*NL + l)*NC + oc0;
  #pragma unroll
  for (int g=0; g<2; ++g){
    half8 h;
    #pragma unroll
    for (int j=0; j<8; ++j) h[j] = (_Float16)acc[g*8+j];
    *(half8*)(yo + g*8) = h;
  }
}

__global__ void k_codes(const float* __restrict__ xe, const float* __restrict__ rot,
                        int* __restrict__ codes){
  int gid = blockIdx.x*256 + threadIdx.x;
  if (gid >= NB*NHASH*NL) return;
  int l = gid & (NL-1); int t = gid >> 14; int h = t & 3; int bb = t >> 2;
  const float* v = xe + (size_t)(bb*NL + l)*NCR;
  float q[16];
  #pragma unroll
  for (int f=0; f<16; ++f) q[f] = v[f];
  float rv[16];
  #pragma unroll
  for (int i=0; i<16; ++i){
    float s = 0.f;
    #pragma unroll
    for (int f=0; f<16; ++f) s += q[f]*rot[(f*NHASH + h)*16 + i];
    rv[i] = s;
  }
  float best = -1e30f; int bi = 0;
  #pragma unroll
  for (int i=0; i<16; ++i){ if (rv[i] > best){ best = rv[i]; bi = i; } }
  #pragma unroll
  for (int i=0; i<16; ++i){ float val = -rv[i]; if (val > best){ best = val; bi = 16+i; } }
  codes[gid] = bi + h*32;
}

__global__ void k_zero(int* __restrict__ p, int n){
  int i = blockIdx.x*256 + threadIdx.x;
  if (i < n) p[i] = 0;
}

__global__ void k_hist(const int* __restrict__ codes, int* __restrict__ hist){
  __shared__ int h[NKEY];
  int bt = blockIdx.x; int bb = bt >> 8; int tile = bt & 255;
  int tid = threadIdx.x;
  h[tid] = 0; __syncthreads();
  for (int i = tid; i < TILESZ; i += 128)
    atomicAdd(&h[codes[bb*TOT + tile*TILESZ + i]], 1);
  __syncthreads();
  hist[bb*NKEY*NTILE + tid*NTILE + tile] = h[tid];
}

__global__ void k_scan(const int* __restrict__ hist, int* __restrict__ offs){
  __shared__ int part[256];
  int bb = blockIdx.x; int t = threadIdx.x;
  const int* hi = hist + (size_t)bb*NKEY*NTILE;
  int* oo = offs + (size_t)bb*NKEY*NTILE;
  int s = 0;
  for (int i=0; i<128; ++i) s += hi[t*128 + i];
  part[t] = s; __syncthreads();
  if (t == 0){ int acc = 0; for (int i=0;i<256;++i){ int v=part[i]; part[i]=acc; acc+=v; } }
  __syncthreads();
  int run = part[t];
  for (int i=0; i<128; ++i){ int v = hi[t*128+i]; oo[t*128+i] = run; run += v; }
}

__global__ void k_scatter(const int* __restrict__ codes, const int* __restrict__ offs,
                          int* __restrict__ idx, int* __restrict__ undo){
  __shared__ int cnt[NKEY];
  int tid = threadIdx.x;
  cnt[tid] = 0; __syncthreads();
  if (tid == 0){
    int bt = blockIdx.x; int bb = bt >> 8; int tile = bt & 255;
    const int* cb = codes + bb*TOT;
    const int* ob = offs + (size_t)bb*NKEY*NTILE;
    int* ib = idx + bb*TOT;
    int* ub = undo + bb*TOT;
    #pragma unroll 4
    for (int i=0; i<TILESZ; ++i){
      int j = tile*TILESZ + i;
      int k = cb[j];
      int pos = ob[k*NTILE + tile] + cnt[k]++;
      ib[pos] = j;
      ub[j] = pos;
    }
  }
}

// MFMA flash attention (unchanged)
__global__ __launch_bounds__(512) void k_attn(
    const _Float16* __restrict__ xeh, const _Float16* __restrict__ xenh,
    const _Float16* __restrict__ yeh, const int* __restrict__ idx,
    _Float16* __restrict__ retb, float* __restrict__ bsc){
  __shared__ _Float16 kt[64*24];
  __shared__ _Float16 vt[64*72];
  int blk = blockIdx.x;
  int kk = blk & 31; int h = (blk >> 5) & 3; int bb = blk >> 7;
  int tid = threadIdx.x;
  int w = tid >> 6, lane = tid & 63, col = lane & 15, grp = lane >> 4;
  const int* idxb = idx + bb*TOT;
  int qbase = h*NL + kk*CHUNKSZ + w*64;

  half4 qfr[4]; int posq[4];
  #pragma unroll
  for (int qf=0; qf<4; ++qf){
    posq[qf] = qbase + qf*16 + col;
    int lq = idxb[posq[qf]] & (NL-1);
    qfr[qf] = *(const half4*)(xeh + ((size_t)bb*NL + lq)*16 + grp*4);
  }

  f32x4 O[4][4];
  #pragma unroll
  for (int a=0; a<4; ++a)
    #pragma unroll
    for (int b=0; b<4; ++b) O[a][b] = (f32x4){0.f,0.f,0.f,0.f};
  float m_[4] = {-1e30f,-1e30f,-1e30f,-1e30f};
  float ssum[4] = {0.f,0.f,0.f,0.f};

  for (int t=0; t<24; ++t){
    __syncthreads();
    {
      int kx = tid & 63, c0 = (tid >> 6) * 8;
      int jj = t*64 + kx; int sec = jj >> 9; int j0 = jj & 511;
      int cc = kk + ((sec==1) ? -1 : (sec==2) ? 1 : 0);
      cc = (cc + NCHUNKS) & (NCHUNKS-1);
      int lv = idxb[h*NL + cc*CHUNKSZ + j0] & (NL-1);
      half8 vv = *(const half8*)(yeh + ((size_t)bb*NL + lv)*64 + c0);
      #pragma unroll
      for (int j=0; j<8; ++j) vt[(c0+j)*72 + kx] = vv[j];
    }
    if (tid < 128){
      int r = tid >> 1, hf = tid & 1;
      int jj = t*64 + r; int sec = jj >> 9; int j0 = jj & 511;
      int cc = kk + ((sec==1) ? -1 : (sec==2) ? 1 : 0);
      cc = (cc + NCHUNKS) & (NCHUNKS-1);
      int lk = idxb[h*NL + cc*CHUNKSZ + j0] & (NL-1);
      *(half8*)(kt + r*24 + hf*8) =
          *(const half8*)(xenh + ((size_t)bb*NL + lk)*16 + hf*8);
    }
    __syncthreads();

    f32x4 S[4][4];
    #pragma unroll
    for (int kb=0; kb<4; ++kb){
      half4 ka = *(const half4*)(kt + (kb*16 + col)*24 + grp*4);
      #pragma unroll
      for (int qf=0; qf<4; ++qf)
        S[kb][qf] = __builtin_amdgcn_mfma_f32_16x16x16f16(
            ka, qfr[qf], (f32x4){0.f,0.f,0.f,0.f}, 0, 0, 0);
    }

    half4 pf[4][4];
    #pragma unroll
    for (int qf=0; qf<4; ++qf){
      float mt = -1e30f;
      #pragma unroll
      for (int kb=0; kb<4; ++kb)
        #pragma unroll
        for (int i=0; i<4; ++i) mt = fmaxf(mt, S[kb][qf][i]);
      mt = fmaxf(mt, __shfl_xor(mt, 16, 64));
      mt = fmaxf(mt, __shfl_xor(mt, 32, 64));
      float mn = fmaxf(m_[qf], mt);
      float sc = __expf(m_[qf] - mn);
      float ps = 0.f;
      #pragma unroll
      for (int kb=0; kb<4; ++kb){
        #pragma unroll
        for (int i=0; i<4; ++i){
          float p = __expf(S[kb][qf][i] - mn);
          ps += p;
          pf[qf][kb][i] = (_Float16)p;
        }
      }
      ps += __shfl_xor(ps, 16, 64);
      ps += __shfl_xor(ps, 32, 64);
      ssum[qf] = ssum[qf]*sc + ps;
      m_[qf] = mn;
      #pragma unroll
      for (int cf=0; cf<4; ++cf)
        #pragma unroll
        for (int i=0; i<4; ++i) O[cf][qf][i] *= sc;
    }

    #pragma unroll
    for (int cf=0; cf<4; ++cf){
      #pragma unroll
      for (int kb=0; kb<4; ++kb){
        half4 va = *(const half4*)(vt + (cf*16 + col)*72 + kb*16 + grp*4);
        #pragma unroll
        for (int qf=0; qf<4; ++qf)
          O[cf][qf] = __builtin_amdgcn_mfma_f32_16x16x16f16(
              va, pf[qf][kb], O[cf][qf], 0, 0, 0);
      }
    }
  }

  #pragma unroll
  for (int qf=0; qf<4; ++qf){
    float inv = 1.0f/ssum[qf];
    size_t rb = ((size_t)bb*TOT + posq[qf])*64;
    #pragma unroll
    for (int cf=0; cf<4; ++cf){
      half4 o;
      #pragma unroll
      for (int i=0; i<4; ++i) o[i] = (_Float16)(O[cf][qf][i]*inv);
      *(half4*)(retb + rb + cf*16 + grp*4) = o;
    }
    if (grp == 0) bsc[(size_t)bb*TOT + posq[qf]] = m_[qf] + logf(ssum[qf]);
  }
}

// combine: c split 2-way via blockIdx.y
__global__ __launch_bounds__(256,4) void k_combine(const _Float16* __restrict__ retb,
                          const float* __restrict__ bsc,
                          const int* __restrict__ undo, const float* __restrict__ mask,
                          float* __restrict__ fea){
  int gid = blockIdx.x*256 + threadIdx.x;
  int c0 = blockIdx.y*32;
  int bb = gid >> 14; int l = gid & (NL-1);
  const int* ub = undo + bb*TOT;
  int pos[4]; float sc[4];
  #pragma unroll
  for (int h=0; h<4; ++h){ pos[h] = ub[h*NL + l]; sc[h] = bsc[bb*TOT + pos[h]]; }
  float mx = fmaxf(fmaxf(sc[0],sc[1]), fmaxf(sc[2],sc[3]));
  float e[4]; float tot = 0.f;
  #pragma unroll
  for (int h=0; h<4; ++h){ e[h] = __expf(sc[h]-mx); tot += e[h]; }
  float inv = 0.1f/tot;
  const float* mb_ = mask + (size_t)bb*NC*NL + l;
  float* fo = fea + (size_t)bb*NC*NL + l;
  const _Float16* r0 = retb + ((size_t)bb*TOT + pos[0])*NC + c0;
  const _Float16* r1 = retb + ((size_t)bb*TOT + pos[1])*NC + c0;
  const _Float16* r2 = retb + ((size_t)bb*TOT + pos[2])*NC + c0;
  const _Float16* r3 = retb + ((size_t)bb*TOT + pos[3])*NC + c0;
  #pragma unroll
  for (int g=0; g<4; ++g){
    half8 v0 = *(const half8*)(r0 + g*8);
    half8 v1 = *(const half8*)(r1 + g*8);
    half8 v2 = *(const half8*)(r2 + g*8);
    half8 v3 = *(const half8*)(r3 + g*8);
    #pragma unroll
    for (int j=0; j<8; ++j){
      int c = c0 + g*8 + j;
      float v = (float)v0[j]*e[0] + (float)v1[j]*e[1] + (float)v2[j]*e[2] + (float)v3[j]*e[3];
      fo[(size_t)c*NL] = v*inv + mb_[(size_t)c*NL];
    }
  }
}

// collect: oc split 4-way
__global__ __launch_bounds__(256,4) void k_collect(const float* __restrict__ fea,
                          const float* __restrict__ w,
                          const float* __restrict__ b, const float* __restrict__ x,
                          float* __restrict__ out){
  int gid = blockIdx.x*256 + threadIdx.x;
  int oc0 = blockIdx.y*16;
  int bb = gid >> 14, p = gid & (NL-1);
  const float* fi = fea + (size_t)bb*NC*NL + p;
  const float* xi = x + (size_t)bb*NC*NL + p;
  float acc[16];
  #pragma unroll
  for (int j=0; j<16; ++j) acc[j] = b[oc0+j];
  for (int ic0=0; ic0<64; ic0+=8){
    float r[8];
    #pragma unroll
    for (int j=0; j<8; ++j) r[j] = fi[(size_t)(ic0+j)*NL];
    #pragma unroll
    for (int j=0; j<16; ++j){
      #pragma unroll
      for (int t=0; t<8; ++t) acc[j] += r[t]*w[(oc0+j)*64+ic0+t];
    }
  }
  float* oo = out + (size_t)bb*NC*NL + p;
  #pragma unroll
  for (int j=0; j<16; ++j){
    int oc = oc0 + j;
    oo[(size_t)oc*NL] = acc[j] + xi[(size_t)oc*NL];
  }
}

// ---------------- launcher ----------------
extern "C" void kernel_launch(void* const* d_in, const int* in_sizes, int n_in,
                              void* d_out, int out_size, void* d_ws, size_t ws_size,
                              hipStream_t stream) {
  const float* x        = (const float*)d_in[0];
  const float* spa_dw   = (const float*)d_in[1];
  const float* spa_db   = (const float*)d_in[2];
  const float* s0_pw    = (const float*)d_in[3];
  const float* s0_dww   = (const float*)d_in[4];
  const float* s0_dwb   = (const float*)d_in[5];
  const float* fus_w    = (const float*)d_in[15];
  const float* fus_b    = (const float*)d_in[16];
  const float* res_w    = (const float*)d_in[17];
  const float* res_b    = (const float*)d_in[18];
  const float* ca_w1    = (const float*)d_in[19];
  const float* ca_b1    = (const float*)d_in[20];
  const float* ca_w2    = (const float*)d_in[21];
  const float* ca_b2    = (const float*)d_in[22];
  const float* c11_w    = (const float*)d_in[23];
  const float* c11_b    = (const float*)d_in[24];
  const float* match_w  = (const float*)d_in[25];
  const float* match_b  = (const float*)d_in[26];
  const float* asm_w    = (const float*)d_in[27];
  const float* asm_b    = (const float*)d_in[28];
  const float* rot      = (const float*)d_in[29];
  const float* col_w    = (const float*)d_in[30];
  const float* col_b    = (const float*)d_in[31];
  float* out = (float*)d_out;

  float* ws    = (float*)d_ws;
  float* mask  = ws + OFF_MASK;
  float* fea   = ws + OFF_FEA;
  float* xe    = ws + OFF_XE;
  _Float16* xeh  = (_Float16*)(ws + OFF_XEH);
  _Float16* xenh = (_Float16*)(ws + OFF_XENH);
  _Float16* yeh  = (_Float16*)(ws + OFF_YEH);
  _Float16* retb = (_Float16*)(ws + OFF_RET);
  float* bsc   = ws + OFF_BSC;
  int*   ib    = (int*)(ws + OFF_INT);
  int* codes   = ib + IOFF_CODES;
  int* idx     = ib + IOFF_IDX;
  int* undo    = ib + IOFF_UNDO;
  int* hist    = ib + IOFF_HIST;
  int* offs    = ib + IOFF_OFFS;
  float* cay   = ws + OFF_CAY;
  float* cas   = ws + OFF_CAS;
  float* crw   = ws + OFF_CRW;
  float* crb   = ws + OFF_CRB;
  float* xr    = ws + OFF_XR;
  float* feats = ws + OFF_FEATS;
  float* pmx   = ws + OFF_PMX;
  float* pav   = ws + OFF_PAV;
  float* ptmp  = ws + OFF_PTMP;
  float* dwt   = ws + OFF_DWT;
  float* pre1  = ws + OFF_PRE1;

  // ---- phase 1 ----
  k_xr<<<(NB*NL*2)/256, 256, 0, stream>>>(x, spa_dw, spa_db, xr);
  k_wprod<<<16, 256, 0, stream>>>(c11_w, c11_b, res_w, res_b, crw, crb);
  k_s0<<<dim3((NB*NL)/256, 2), 256, 0, stream>>>(xr, s0_pw, s0_dww, s0_dwb, feats);
  k_pool<<<(NB*NCR*NL2)/256, 256, 0, stream>>>(xr, pmx, pav);
  k_pw16_all<<<(6*NB*NL2)/256, 256, 0, stream>>>(pmx, pav,
      (const float*)d_in[6], (const float*)d_in[9], (const float*)d_in[12], ptmp);
  k_dw_all<<<(6*NB*NCR*NL2)/256, 256, 0, stream>>>(ptmp,
      (const float*)d_in[7], (const float*)d_in[8],
      (const float*)d_in[10], (const float*)d_in[11],
      (const float*)d_in[13], (const float*)d_in[14], dwt);
  k_up_all<<<(6*NB*NCR*NL)/256, 256, 0, stream>>>(dwt, feats);
  k_camean<<<NB*NC, 256, 0, stream>>>(x, cay);
  k_camlp<<<1, 128, 0, stream>>>(cay, ca_w1, ca_b1, ca_w2, ca_b2, cas);
  k_attnmul<<<dim3((NB*NL)/256, 4), 256, 0, stream>>>(x, feats, fus_w, fus_b, cas, pre1);
  k_mask<<<dim3((NB*NL)/256, 4), 256, 0, stream>>>(pre1, c11_w, crw, crb, x, mask);

  // ---- phase 2 ----
  k_xe<<<(NB*NL*2)/256, 256, 0, stream>>>(mask, match_w, match_b, xe, xeh, xenh);
  k_yeh<<<dim3((NB*NL)/256, 4), 256, 0, stream>>>(mask, asm_w, asm_b, yeh);
  k_codes<<<(NB*NHASH*NL)/256, 256, 0, stream>>>(xe, rot, codes);
  k_zero<<<(NB*NKEY*NTILE + 255)/256, 256, 0, stream>>>(hist, NB*NKEY*NTILE);
  k_hist<<<NB*NTILE, 128, 0, stream>>>(codes, hist);
  k_scan<<<NB, 256, 0, stream>>>(hist, offs);
  k_scatter<<<NB*NTILE, 128, 0, stream>>>(codes, offs, idx, undo);
  k_attn<<<NB*NHASH*NCHUNKS, 512, 0, stream>>>(xeh, xenh, yeh, idx, retb, bsc);
  k_combine<<<dim3((NB*NL)/256, 2), 256, 0, stream>>>(retb, bsc, undo, mask, fea);
  k_collect<<<dim3((NB*NL)/256, 4), 256, 0, stream>>>(fea, col_w, col_b, x, out);
}